// Round 2
// baseline (1080.564 us; speedup 1.0000x reference)
//
#include <hip/hip_runtime.h>
#include <cstdint>
#include <cstddef>

// GraphConvolution: out = (A_sparse @ x) @ W^T + b   (N=100000, E=3.2M, D=256)
// Pipeline: hist -> scan(+deg hist/scan) -> deg-sort perm -> CSR scatter
//           -> castXW(bf16) -> gather (deg-balanced waves, reg acc)
//           -> bf16 MFMA GEMM (agg @ W^T + b).
// NOTE: never use the 2nd __launch_bounds__ arg here — R2/R3 showed it caps
// VGPRs to ~84 and forces ~2.3 GB of scratch spill traffic in the gather.
// R4: bf16 x halves per-edge bytes (512B) — gather was byte-bound. 495->310us.
// R5(this): degree-sorted node assignment (counting sort, descending) removes
// the ~25% max-of-8 degree padding in gather; cursor pre-init removes the
// random row_start reads in scatter.
#define D 256
#define NPB 32
#define SCAN_CHUNK 2048

typedef __attribute__((ext_vector_type(8))) short short8;
typedef __attribute__((ext_vector_type(4))) float floatx4;

__device__ __forceinline__ unsigned short f2bf(float f) {
    union { float f; unsigned int u; } cv; cv.f = f;
    unsigned int u = cv.u;
    unsigned int r = (u + 0x7fffu + ((u >> 16) & 1u)) >> 16;  // RNE
    return (unsigned short)r;
}

__device__ __forceinline__ float bf2f(unsigned short s) {
    union { unsigned int u; float f; } cv;
    cv.u = ((unsigned int)s) << 16;
    return cv.f;
}

__global__ void k_hist(const int* __restrict__ erow, int* __restrict__ counts, int e) {
    int i = blockIdx.x * blockDim.x + threadIdx.x;
    if (i < e) atomicAdd(&counts[erow[i]], 1);
}

// Row-offset scan chunk + degree histogram (256 bins, b = 255-min(deg,255)
// so an ascending scan of bins yields DESCENDING degree order).
__global__ void k_scan1(const int* __restrict__ counts, int* __restrict__ row_start,
                        int* __restrict__ blk_sums, int* __restrict__ dhist, int n) {
    __shared__ int sd[256];
    __shared__ int dh[256];
    int tid = threadIdx.x;
    dh[tid] = 0;
    int base = blockIdx.x * SCAN_CHUNK + tid * 8;
    int v[8];
    int s = 0;
#pragma unroll
    for (int i = 0; i < 8; ++i) {
        int idx = base + i;
        v[i] = (idx < n) ? counts[idx] : 0;
        s += v[i];
    }
    sd[tid] = s;
    __syncthreads();  // also publishes dh zeroing
    for (int off = 1; off < 256; off <<= 1) {
        int t = (tid >= off) ? sd[tid - off] : 0;
        __syncthreads();
        sd[tid] += t;
        __syncthreads();
    }
    int run = sd[tid] - s;
    if (tid == 255) blk_sums[blockIdx.x] = sd[255];
#pragma unroll
    for (int i = 0; i < 8; ++i) {
        int idx = base + i;
        if (idx < n) {
            row_start[idx] = run;
            atomicAdd(&dh[255 - min(v[i], 255)], 1);
        }
        run += v[i];
    }
    __syncthreads();
    if (dh[tid]) atomicAdd(&dhist[tid], dh[tid]);
}

// Chunk-sum scan (thread 0 serial over <=64 chunks) + parallel 256-bin degree
// scan -> dstart.
__global__ void k_scan2(int* __restrict__ blk_sums, int* __restrict__ row_start,
                        const int* __restrict__ dhist, int* __restrict__ dstart,
                        int nch, int n) {
    __shared__ int sd[64];
    __shared__ int dh[256];
    int tid = threadIdx.x;
    if (tid < nch) sd[tid] = blk_sums[tid];
    dh[tid] = dhist[tid];
    __syncthreads();
    if (tid == 0) {
        int run = 0;
        for (int b = 0; b < nch; ++b) { int t = sd[b]; sd[b] = run; run += t; }
        row_start[n] = run;
    }
    __syncthreads();
    if (tid < nch) blk_sums[tid] = sd[tid];
    int own = dh[tid];
    for (int off = 1; off < 256; off <<= 1) {
        int t = (tid >= off) ? dh[tid - off] : 0;
        __syncthreads();
        dh[tid] += t;
        __syncthreads();
    }
    dstart[tid] = dh[tid] - own;
}

// Finalize row_start and seed cursor = row_start (scatter then needs only the
// atomicAdd — no random row_start reads).
__global__ void k_scan3(int* __restrict__ row_start, const int* __restrict__ blk_sums,
                        int* __restrict__ cursor, int n) {
    int i = blockIdx.x * blockDim.x + threadIdx.x;
    if (i < n) {
        int v = row_start[i] + blk_sums[i >> 11];
        row_start[i] = v;
        cursor[i] = v;
    }
}

// Counting-sort scatter: perm = node ids in descending-degree order.
__global__ void k_dscatter(const int* __restrict__ counts, const int* __restrict__ dstart,
                           int* __restrict__ dcur, int* __restrict__ perm, int n) {
    int i = blockIdx.x * blockDim.x + threadIdx.x;
    if (i < n) {
        int b = 255 - min(counts[i], 255);
        perm[dstart[b] + atomicAdd(&dcur[b], 1)] = i;
    }
}

__global__ void k_scatter(const int* __restrict__ erow, const int* __restrict__ ecol,
                          const float* __restrict__ eval,
                          int* __restrict__ cursor, int2* __restrict__ sedge, int e) {
    int i = blockIdx.x * blockDim.x + threadIdx.x;
    if (i < e) {
        int r = erow[i];
        int p = atomicAdd(&cursor[r], 1);
        sedge[p] = make_int2(ecol[i], __float_as_int(eval[i]));
    }
}

// Cast x (fp32, 102 MB) -> bf16 (51 MB); first 8192 threads also cast W.
__global__ void k_castXW(const float* __restrict__ x, unsigned short* __restrict__ xb,
                         const float* __restrict__ W, unsigned short* __restrict__ Wb) {
    size_t gid = (size_t)blockIdx.x * blockDim.x + threadIdx.x;
    size_t i = gid * 8;
    float4 a = *(const float4*)&x[i];
    float4 b = *(const float4*)&x[i + 4];
    short8 v;
    v[0] = (short)f2bf(a.x); v[1] = (short)f2bf(a.y);
    v[2] = (short)f2bf(a.z); v[3] = (short)f2bf(a.w);
    v[4] = (short)f2bf(b.x); v[5] = (short)f2bf(b.y);
    v[6] = (short)f2bf(b.z); v[7] = (short)f2bf(b.w);
    *(short8*)&xb[i] = v;
    if (gid < 8192) {
        float4 c = *(const float4*)&W[gid * 8];
        float4 d = *(const float4*)&W[gid * 8 + 4];
        short8 w;
        w[0] = (short)f2bf(c.x); w[1] = (short)f2bf(c.y);
        w[2] = (short)f2bf(c.z); w[3] = (short)f2bf(c.w);
        w[4] = (short)f2bf(d.x); w[5] = (short)f2bf(d.y);
        w[6] = (short)f2bf(d.z); w[7] = (short)f2bf(d.w);
        *(short8*)&Wb[gid * 8] = w;
    }
}

// Gather: each wave owns 8 nodes IN PARALLEL (8 independent load chains per
// iteration = MLP). Nodes come from the descending-degree perm, so the 8
// degrees are near-identical -> ~no max-degree padding waste. No LDS,
// register fp32 accumulators, bf16 x rows (512B/edge), bf16 output rows.
__global__ __launch_bounds__(256) void k_gather(
    const unsigned short* __restrict__ xb, const int2* __restrict__ sedge,
    const int* __restrict__ row_start, const int* __restrict__ perm,
    unsigned short* __restrict__ aggb, int n) {
    const int tid = threadIdx.x;
    const int lane = tid & 63;
    const int wv = tid >> 6;
    const int base = blockIdx.x * NPB + wv * 8;

    int pn[8], ebeg[8], eend[8];
    int maxd = 0;
#pragma unroll
    for (int j = 0; j < 8; ++j) {
        pn[j] = perm[base + j];
        ebeg[j] = row_start[pn[j]];
        eend[j] = row_start[pn[j] + 1];
        maxd = max(maxd, eend[j] - ebeg[j]);
    }
    float4 acc[8];
#pragma unroll
    for (int j = 0; j < 8; ++j) acc[j] = make_float4(0.f, 0.f, 0.f, 0.f);

    for (int it = 0; it < maxd; ++it) {
        int2 ev[8];
        ushort4 xv[8];
#pragma unroll
        for (int j = 0; j < 8; ++j) {
            int e = ebeg[j] + it;
            int ec = max(min(e, eend[j] - 1), 0);  // clamped: always valid
            ev[j] = sedge[ec];
        }
#pragma unroll
        for (int j = 0; j < 8; ++j) {
            // 8B/lane, 512B/wave coalesced bf16 row slice
            xv[j] = *(const ushort4*)&xb[(size_t)ev[j].x * D + lane * 4];
        }
#pragma unroll
        for (int j = 0; j < 8; ++j) {
            float v = (ebeg[j] + it < eend[j]) ? __int_as_float(ev[j].y) : 0.f;
            acc[j].x += v * bf2f(xv[j].x);
            acc[j].y += v * bf2f(xv[j].y);
            acc[j].z += v * bf2f(xv[j].z);
            acc[j].w += v * bf2f(xv[j].w);
        }
    }
#pragma unroll
    for (int j = 0; j < 8; ++j) {
        ushort4 u;
        u.x = f2bf(acc[j].x);
        u.y = f2bf(acc[j].y);
        u.z = f2bf(acc[j].z);
        u.w = f2bf(acc[j].w);
        *(ushort4*)&aggb[(size_t)pn[j] * D + lane * 4] = u;  // 512B/row
    }
}

// GEMM: out[m][o] = sum_k aggb[m][k] * Wb[o][k] + bias[o], bf16 MFMA.
// Block = 4 waves x 16 rows = 64-row M-tile, full N=256, K chunked by 64.
// A-frag: A[m=lane&15][k=quad*8+j]; B-frag: B[k=quad*8+j][n=lane&15] with
// B[k][n] = W[n][k] (16B contiguous from row-major W). C/D: col=lane&15,
// row=quad*4+reg (m89-verified). LDS W rows padded to 72 bf16 -> balanced banks.
__global__ __launch_bounds__(256) void k_gemm(
    const unsigned short* __restrict__ aggb, const unsigned short* __restrict__ Wb,
    const float* __restrict__ bias, float* __restrict__ out, int M) {
    __shared__ __align__(16) unsigned short Wl[256 * 72];  // 36 KB

    const int tid = threadIdx.x;
    const int lane = tid & 63;
    const int wv = tid >> 6;
    const int col = lane & 15;
    const int quad = lane >> 4;
    const int bm = blockIdx.x * 64 + wv * 16;

    floatx4 acc[16];
#pragma unroll
    for (int i = 0; i < 16; ++i) acc[i] = (floatx4){0.f, 0.f, 0.f, 0.f};

    const int arow = min(bm + col, M - 1);  // clamp (stores are guarded)

    for (int kc = 0; kc < 4; ++kc) {
        __syncthreads();
        // stage W[0..255][kc*64 .. +63] -> Wl, thread t = row t (8x 16B)
        {
            const uint4* src = (const uint4*)(Wb + (size_t)tid * D + kc * 64);
#pragma unroll
            for (int s = 0; s < 8; ++s) {
                *(uint4*)&Wl[tid * 72 + s * 8] = src[s];
            }
        }
        __syncthreads();

        short8 a[2];
#pragma unroll
        for (int t2 = 0; t2 < 2; ++t2) {
            a[t2] = *(const short8*)&aggb[(size_t)arow * D + kc * 64 + t2 * 32 + quad * 8];
        }
#pragma unroll
        for (int i = 0; i < 16; ++i) {
#pragma unroll
            for (int t2 = 0; t2 < 2; ++t2) {
                short8 b = *(const short8*)&Wl[(i * 16 + col) * 72 + t2 * 32 + quad * 8];
                acc[i] = __builtin_amdgcn_mfma_f32_16x16x32_bf16(a[t2], b, acc[i], 0, 0, 0);
            }
        }
    }

#pragma unroll
    for (int i = 0; i < 16; ++i) {
        int o = i * 16 + col;
        float bv = bias[o];
#pragma unroll
        for (int r = 0; r < 4; ++r) {
            int m = bm + quad * 4 + r;
            if (m < M) out[(size_t)m * D + o] = acc[i][r] + bv;
        }
    }
}

extern "C" void kernel_launch(void* const* d_in, const int* in_sizes, int n_in,
                              void* d_out, int out_size, void* d_ws, size_t ws_size,
                              hipStream_t stream) {
    const float* x    = (const float*)d_in[0];
    const int*   erow = (const int*)d_in[1];
    const int*   ecol = (const int*)d_in[2];
    const float* eval = (const float*)d_in[3];
    const float* W    = (const float*)d_in[4];
    const float* bias = (const float*)d_in[5];
    float* out = (float*)d_out;

    const int n = in_sizes[0] / D;  // 100000
    const int e = in_sizes[1];      // 3200000

    // ws: counts[n] | dhist[256] | dcur[256] | dstart[256] | cursor[n]
    //     | blk_sums[64] | row_start[n+1] | perm[n] | sedge[e] int2
    //     | Wb[65536] u16 | aggb[n*256] u16 | xb[n*256] u16
    int* counts    = (int*)d_ws;
    int* dhist     = counts + n;
    int* dcur      = dhist + 256;
    int* dstart    = dcur + 256;
    int* cursor    = dstart + 256;
    int* blk_sums  = cursor + n;
    int* row_start = blk_sums + 64;
    int* perm      = row_start + n + 1;
    int2* sedge    = (int2*)(((uintptr_t)(perm + n) + 15) & ~(uintptr_t)15);
    unsigned short* Wb   = (unsigned short*)(sedge + e);
    unsigned short* aggb = Wb + 65536;
    unsigned short* xb   = aggb + (size_t)n * D;

    // zero: counts + dhist + dcur (dstart/cursor/blk_sums are fully written)
    hipMemsetAsync(counts, 0, (size_t)(n + 512) * sizeof(int), stream);

    const int nch = (n + SCAN_CHUNK - 1) / SCAN_CHUNK;  // 49

    k_hist<<<(e + 255) / 256, 256, 0, stream>>>(erow, counts, e);
    k_scan1<<<nch, 256, 0, stream>>>(counts, row_start, blk_sums, dhist, n);
    k_scan2<<<1, 256, 0, stream>>>(blk_sums, row_start, dhist, dstart, nch, n);
    k_scan3<<<(n + 255) / 256, 256, 0, stream>>>(row_start, blk_sums, cursor, n);
    k_dscatter<<<(n + 255) / 256, 256, 0, stream>>>(counts, dstart, dcur, perm, n);
    k_castXW<<<(n * D / 8 + 255) / 256, 256, 0, stream>>>(x, xb, W, Wb);
    k_scatter<<<(e + 255) / 256, 256, 0, stream>>>(erow, ecol, eval, cursor, sedge, e);
    k_gather<<<n / NPB, 256, 0, stream>>>(xb, sedge, row_start, perm, aggb, n);
    k_gemm<<<(n + 63) / 64, 256, 0, stream>>>(aggb, Wb, bias, out, n);
}

// Round 3
// 913.236 us; speedup vs baseline: 1.1832x; 1.1832x over previous
//
#include <hip/hip_runtime.h>
#include <cstdint>
#include <cstddef>

// GraphConvolution: out = (A_sparse @ x) @ W^T + b   (N=100000, E=3.2M, D=256)
// Pipeline: hist -> scan(+deg hist/scan) -> deg-sort perm -> CSR scatter
//           -> castXW(bf16) -> gather (deg-balanced waves, reg acc)
//           -> bf16 MFMA GEMM (agg @ W^T + b).
// NOTE: never use the 2nd __launch_bounds__ arg here — R2/R3 showed it caps
// VGPRs to ~84 and forces ~2.3 GB of scratch spill traffic in the gather.
// R4: bf16 x halves per-edge bytes (512B) — gather was byte-bound. 495->310us.
// R5: degree-sorted node assignment removes max-of-8 padding (gather 310->278)
//     BUT naive counting-sort dscatter serialized ~7K atomics on hot degree
//     bins (+250us). R6(this): block-aggregated sort — LDS local hist + one
//     global atomicAdd per (block,bin) chunk reservation. ~2.5K global atomics
//     total, <=49 serialized per bin.
#define D 256
#define NPB 32
#define SCAN_CHUNK 2048

typedef __attribute__((ext_vector_type(8))) short short8;
typedef __attribute__((ext_vector_type(4))) float floatx4;

__device__ __forceinline__ unsigned short f2bf(float f) {
    union { float f; unsigned int u; } cv; cv.f = f;
    unsigned int u = cv.u;
    unsigned int r = (u + 0x7fffu + ((u >> 16) & 1u)) >> 16;  // RNE
    return (unsigned short)r;
}

__device__ __forceinline__ float bf2f(unsigned short s) {
    union { unsigned int u; float f; } cv;
    cv.u = ((unsigned int)s) << 16;
    return cv.f;
}

__global__ void k_hist(const int* __restrict__ erow, int* __restrict__ counts, int e) {
    int i = blockIdx.x * blockDim.x + threadIdx.x;
    if (i < e) atomicAdd(&counts[erow[i]], 1);
}

// Row-offset scan chunk + degree histogram (256 bins, b = 255-min(deg,255)
// so an ascending scan of bins yields DESCENDING degree order).
__global__ void k_scan1(const int* __restrict__ counts, int* __restrict__ row_start,
                        int* __restrict__ blk_sums, int* __restrict__ dhist, int n) {
    __shared__ int sd[256];
    __shared__ int dh[256];
    int tid = threadIdx.x;
    dh[tid] = 0;
    int base = blockIdx.x * SCAN_CHUNK + tid * 8;
    int v[8];
    int s = 0;
#pragma unroll
    for (int i = 0; i < 8; ++i) {
        int idx = base + i;
        v[i] = (idx < n) ? counts[idx] : 0;
        s += v[i];
    }
    sd[tid] = s;
    __syncthreads();  // also publishes dh zeroing
    for (int off = 1; off < 256; off <<= 1) {
        int t = (tid >= off) ? sd[tid - off] : 0;
        __syncthreads();
        sd[tid] += t;
        __syncthreads();
    }
    int run = sd[tid] - s;
    if (tid == 255) blk_sums[blockIdx.x] = sd[255];
#pragma unroll
    for (int i = 0; i < 8; ++i) {
        int idx = base + i;
        if (idx < n) {
            row_start[idx] = run;
            atomicAdd(&dh[255 - min(v[i], 255)], 1);
        }
        run += v[i];
    }
    __syncthreads();
    if (dh[tid]) atomicAdd(&dhist[tid], dh[tid]);
}

// Chunk-sum scan (thread 0 serial over <=64 chunks) + parallel 256-bin degree
// scan -> dcur (seeded bin cursors for the block-chunk reservations).
__global__ void k_scan2(int* __restrict__ blk_sums, int* __restrict__ row_start,
                        const int* __restrict__ dhist, int* __restrict__ dcur,
                        int nch, int n) {
    __shared__ int sd[64];
    __shared__ int dh[256];
    int tid = threadIdx.x;
    if (tid < nch) sd[tid] = blk_sums[tid];
    dh[tid] = dhist[tid];
    __syncthreads();
    if (tid == 0) {
        int run = 0;
        for (int b = 0; b < nch; ++b) { int t = sd[b]; sd[b] = run; run += t; }
        row_start[n] = run;
    }
    __syncthreads();
    if (tid < nch) blk_sums[tid] = sd[tid];
    int own = dh[tid];
    for (int off = 1; off < 256; off <<= 1) {
        int t = (tid >= off) ? dh[tid - off] : 0;
        __syncthreads();
        dh[tid] += t;
        __syncthreads();
    }
    dcur[tid] = dh[tid] - own;  // exclusive bin start
}

// Finalize row_start and seed cursor = row_start (scatter then needs only the
// atomicAdd — no random row_start reads).
__global__ void k_scan3(int* __restrict__ row_start, const int* __restrict__ blk_sums,
                        int* __restrict__ cursor, int n) {
    int i = blockIdx.x * blockDim.x + threadIdx.x;
    if (i < n) {
        int v = row_start[i] + blk_sums[i >> 11];
        row_start[i] = v;
        cursor[i] = v;
    }
}

// Counting-sort scatter, block-aggregated: LDS local histogram + local ranks,
// ONE global atomicAdd per (block, bin) to reserve a contiguous chunk, then
// write perm. Max 49 serialized atomics per bin (vs ~7000 in the naive form).
__global__ __launch_bounds__(256) void k_dscatter(
    const int* __restrict__ counts, int* __restrict__ dcur,
    int* __restrict__ perm, int n) {
    __shared__ int lh[256];    // local histogram / then unused
    __shared__ int lbase[256]; // global chunk base per bin
    const int tid = threadIdx.x;
    lh[tid] = 0;
    __syncthreads();
    const int base = blockIdx.x * SCAN_CHUNK + tid * 8;
    int b[8], rank[8];
#pragma unroll
    for (int i = 0; i < 8; ++i) {
        int idx = base + i;
        if (idx < n) {
            b[i] = 255 - min(counts[idx], 255);
            rank[i] = atomicAdd(&lh[b[i]], 1);
        }
    }
    __syncthreads();
    if (lh[tid]) lbase[tid] = atomicAdd(&dcur[tid], lh[tid]);
    __syncthreads();
#pragma unroll
    for (int i = 0; i < 8; ++i) {
        int idx = base + i;
        if (idx < n) perm[lbase[b[i]] + rank[i]] = idx;
    }
}

__global__ void k_scatter(const int* __restrict__ erow, const int* __restrict__ ecol,
                          const float* __restrict__ eval,
                          int* __restrict__ cursor, int2* __restrict__ sedge, int e) {
    int i = blockIdx.x * blockDim.x + threadIdx.x;
    if (i < e) {
        int r = erow[i];
        int p = atomicAdd(&cursor[r], 1);
        sedge[p] = make_int2(ecol[i], __float_as_int(eval[i]));
    }
}

// Cast x (fp32, 102 MB) -> bf16 (51 MB); first 8192 threads also cast W.
__global__ void k_castXW(const float* __restrict__ x, unsigned short* __restrict__ xb,
                         const float* __restrict__ W, unsigned short* __restrict__ Wb) {
    size_t gid = (size_t)blockIdx.x * blockDim.x + threadIdx.x;
    size_t i = gid * 8;
    float4 a = *(const float4*)&x[i];
    float4 b = *(const float4*)&x[i + 4];
    short8 v;
    v[0] = (short)f2bf(a.x); v[1] = (short)f2bf(a.y);
    v[2] = (short)f2bf(a.z); v[3] = (short)f2bf(a.w);
    v[4] = (short)f2bf(b.x); v[5] = (short)f2bf(b.y);
    v[6] = (short)f2bf(b.z); v[7] = (short)f2bf(b.w);
    *(short8*)&xb[i] = v;
    if (gid < 8192) {
        float4 c = *(const float4*)&W[gid * 8];
        float4 d = *(const float4*)&W[gid * 8 + 4];
        short8 w;
        w[0] = (short)f2bf(c.x); w[1] = (short)f2bf(c.y);
        w[2] = (short)f2bf(c.z); w[3] = (short)f2bf(c.w);
        w[4] = (short)f2bf(d.x); w[5] = (short)f2bf(d.y);
        w[6] = (short)f2bf(d.z); w[7] = (short)f2bf(d.w);
        *(short8*)&Wb[gid * 8] = w;
    }
}

// Gather: each wave owns 8 nodes IN PARALLEL (8 independent load chains per
// iteration = MLP). Nodes come from the descending-degree perm, so the 8
// degrees are near-identical -> ~no max-degree padding waste. No LDS,
// register fp32 accumulators, bf16 x rows (512B/edge), bf16 output rows.
__global__ __launch_bounds__(256) void k_gather(
    const unsigned short* __restrict__ xb, const int2* __restrict__ sedge,
    const int* __restrict__ row_start, const int* __restrict__ perm,
    unsigned short* __restrict__ aggb, int n) {
    const int tid = threadIdx.x;
    const int lane = tid & 63;
    const int wv = tid >> 6;
    const int base = blockIdx.x * NPB + wv * 8;

    int pn[8], ebeg[8], eend[8];
    int maxd = 0;
#pragma unroll
    for (int j = 0; j < 8; ++j) {
        pn[j] = perm[base + j];
        ebeg[j] = row_start[pn[j]];
        eend[j] = row_start[pn[j] + 1];
        maxd = max(maxd, eend[j] - ebeg[j]);
    }
    float4 acc[8];
#pragma unroll
    for (int j = 0; j < 8; ++j) acc[j] = make_float4(0.f, 0.f, 0.f, 0.f);

    for (int it = 0; it < maxd; ++it) {
        int2 ev[8];
        ushort4 xv[8];
#pragma unroll
        for (int j = 0; j < 8; ++j) {
            int e = ebeg[j] + it;
            int ec = max(min(e, eend[j] - 1), 0);  // clamped: always valid
            ev[j] = sedge[ec];
        }
#pragma unroll
        for (int j = 0; j < 8; ++j) {
            // 8B/lane, 512B/wave coalesced bf16 row slice
            xv[j] = *(const ushort4*)&xb[(size_t)ev[j].x * D + lane * 4];
        }
#pragma unroll
        for (int j = 0; j < 8; ++j) {
            float v = (ebeg[j] + it < eend[j]) ? __int_as_float(ev[j].y) : 0.f;
            acc[j].x += v * bf2f(xv[j].x);
            acc[j].y += v * bf2f(xv[j].y);
            acc[j].z += v * bf2f(xv[j].z);
            acc[j].w += v * bf2f(xv[j].w);
        }
    }
#pragma unroll
    for (int j = 0; j < 8; ++j) {
        ushort4 u;
        u.x = f2bf(acc[j].x);
        u.y = f2bf(acc[j].y);
        u.z = f2bf(acc[j].z);
        u.w = f2bf(acc[j].w);
        *(ushort4*)&aggb[(size_t)pn[j] * D + lane * 4] = u;  // 512B/row
    }
}

// GEMM: out[m][o] = sum_k aggb[m][k] * Wb[o][k] + bias[o], bf16 MFMA.
// Block = 4 waves x 16 rows = 64-row M-tile, full N=256, K chunked by 64.
// A-frag: A[m=lane&15][k=quad*8+j]; B-frag: B[k=quad*8+j][n=lane&15] with
// B[k][n] = W[n][k] (16B contiguous from row-major W). C/D: col=lane&15,
// row=quad*4+reg (m89-verified). LDS W rows padded to 72 bf16 -> balanced banks.
__global__ __launch_bounds__(256) void k_gemm(
    const unsigned short* __restrict__ aggb, const unsigned short* __restrict__ Wb,
    const float* __restrict__ bias, float* __restrict__ out, int M) {
    __shared__ __align__(16) unsigned short Wl[256 * 72];  // 36 KB

    const int tid = threadIdx.x;
    const int lane = tid & 63;
    const int wv = tid >> 6;
    const int col = lane & 15;
    const int quad = lane >> 4;
    const int bm = blockIdx.x * 64 + wv * 16;

    floatx4 acc[16];
#pragma unroll
    for (int i = 0; i < 16; ++i) acc[i] = (floatx4){0.f, 0.f, 0.f, 0.f};

    const int arow = min(bm + col, M - 1);  // clamp (stores are guarded)

    for (int kc = 0; kc < 4; ++kc) {
        __syncthreads();
        // stage W[0..255][kc*64 .. +63] -> Wl, thread t = row t (8x 16B)
        {
            const uint4* src = (const uint4*)(Wb + (size_t)tid * D + kc * 64);
#pragma unroll
            for (int s = 0; s < 8; ++s) {
                *(uint4*)&Wl[tid * 72 + s * 8] = src[s];
            }
        }
        __syncthreads();

        short8 a[2];
#pragma unroll
        for (int t2 = 0; t2 < 2; ++t2) {
            a[t2] = *(const short8*)&aggb[(size_t)arow * D + kc * 64 + t2 * 32 + quad * 8];
        }
#pragma unroll
        for (int i = 0; i < 16; ++i) {
#pragma unroll
            for (int t2 = 0; t2 < 2; ++t2) {
                short8 b = *(const short8*)&Wl[(i * 16 + col) * 72 + t2 * 32 + quad * 8];
                acc[i] = __builtin_amdgcn_mfma_f32_16x16x32_bf16(a[t2], b, acc[i], 0, 0, 0);
            }
        }
    }

#pragma unroll
    for (int i = 0; i < 16; ++i) {
        int o = i * 16 + col;
        float bv = bias[o];
#pragma unroll
        for (int r = 0; r < 4; ++r) {
            int m = bm + quad * 4 + r;
            if (m < M) out[(size_t)m * D + o] = acc[i][r] + bv;
        }
    }
}

extern "C" void kernel_launch(void* const* d_in, const int* in_sizes, int n_in,
                              void* d_out, int out_size, void* d_ws, size_t ws_size,
                              hipStream_t stream) {
    const float* x    = (const float*)d_in[0];
    const int*   erow = (const int*)d_in[1];
    const int*   ecol = (const int*)d_in[2];
    const float* eval = (const float*)d_in[3];
    const float* W    = (const float*)d_in[4];
    const float* bias = (const float*)d_in[5];
    float* out = (float*)d_out;

    const int n = in_sizes[0] / D;  // 100000
    const int e = in_sizes[1];      // 3200000

    // ws: counts[n] | dhist[256] | dcur[256] | cursor[n] | blk_sums[64]
    //     | row_start[n+1] | perm[n] | sedge[e] int2
    //     | Wb[65536] u16 | aggb[n*256] u16 | xb[n*256] u16
    int* counts    = (int*)d_ws;
    int* dhist     = counts + n;
    int* dcur      = dhist + 256;
    int* cursor    = dcur + 256;
    int* blk_sums  = cursor + n;
    int* row_start = blk_sums + 64;
    int* perm      = row_start + n + 1;
    int2* sedge    = (int2*)(((uintptr_t)(perm + n) + 15) & ~(uintptr_t)15);
    unsigned short* Wb   = (unsigned short*)(sedge + e);
    unsigned short* aggb = Wb + 65536;
    unsigned short* xb   = aggb + (size_t)n * D;

    // zero: counts + dhist (dcur/cursor/blk_sums are fully written by scans)
    hipMemsetAsync(counts, 0, (size_t)(n + 256) * sizeof(int), stream);

    const int nch = (n + SCAN_CHUNK - 1) / SCAN_CHUNK;  // 49

    k_hist<<<(e + 255) / 256, 256, 0, stream>>>(erow, counts, e);
    k_scan1<<<nch, 256, 0, stream>>>(counts, row_start, blk_sums, dhist, n);
    k_scan2<<<1, 256, 0, stream>>>(blk_sums, row_start, dhist, dcur, nch, n);
    k_scan3<<<(n + 255) / 256, 256, 0, stream>>>(row_start, blk_sums, cursor, n);
    k_dscatter<<<nch, 256, 0, stream>>>(counts, dcur, perm, n);
    k_castXW<<<(n * D / 8 + 255) / 256, 256, 0, stream>>>(x, xb, W, Wb);
    k_scatter<<<(e + 255) / 256, 256, 0, stream>>>(erow, ecol, eval, cursor, sedge, e);
    k_gather<<<n / NPB, 256, 0, stream>>>(xb, sedge, row_start, perm, aggb, n);
    k_gemm<<<(n + 63) / 64, 256, 0, stream>>>(aggb, Wb, bias, out, n);
}

// Round 4
// 866.697 us; speedup vs baseline: 1.2468x; 1.0537x over previous
//
#include <hip/hip_runtime.h>
#include <cstdint>
#include <cstddef>

// GraphConvolution: out = (A_sparse @ x) @ W^T + b   (N=100000, E=3.2M, D=256)
// Pipeline (7 launches): memset -> prep(hist+castX+castWp) -> scan1 -> scan2
//   -> scan3 -> edges(deg-sort + CSR scatter) -> gather+GEMM fused.
// NOTE: never use the 2nd __launch_bounds__ arg here — R2/R3 showed it caps
// VGPRs to ~84 and forces ~2.3 GB of scratch spill traffic in the gather.
// R4: bf16 x halves per-edge bytes (512B) — gather was byte-bound. 495->310us.
// R5: degree-sorted node assignment removes max-of-8 padding (gather 310->278)
// R6: block-aggregated counting sort (LDS hist + 1 atomic per block-bin).
// R7(this): fuse GEMM into gather via LDS agg tile + fragment-ordered W (Wp)
//   -> kills aggb roundtrip (102MB) + separate gemm; fuse casts into hist;
//   fuse deg-sort into scatter. Gather itself is fabric-bound (~3.76 TB/s
//   L2-miss traffic on random 512B x-row reads) — left unchanged.
#define D 256
#define NPB 32
#define SCAN_CHUNK 2048

typedef __attribute__((ext_vector_type(8))) short short8;
typedef __attribute__((ext_vector_type(4))) float floatx4;

__device__ __forceinline__ unsigned short f2bf(float f) {
    union { float f; unsigned int u; } cv; cv.f = f;
    unsigned int u = cv.u;
    unsigned int r = (u + 0x7fffu + ((u >> 16) & 1u)) >> 16;  // RNE
    return (unsigned short)r;
}

__device__ __forceinline__ float bf2f(unsigned short s) {
    union { unsigned int u; float f; } cv;
    cv.u = ((unsigned int)s) << 16;
    return cv.f;
}

// hist (3.2M edge atomics) + castX (102->51MB stream) + castW into
// fragment-ordered Wp. Atomic-latency and streaming-BW pipes overlap.
// Wp layout: flat j = ((ct*8 + ks)*64 + q*16 + l), Wp[j*8..+8] =
//   bf16(W[ct*16 + l][ks*32 + q*8 .. +8])  -> B-frag load is 1KB coalesced.
__global__ void k_prep(const int* __restrict__ erow, int* __restrict__ counts,
                       const float* __restrict__ x, unsigned short* __restrict__ xb,
                       const float* __restrict__ W, unsigned short* __restrict__ Wp,
                       int e, int n) {
    int gid = blockIdx.x * blockDim.x + threadIdx.x;
    if (gid < e) atomicAdd(&counts[erow[gid]], 1);
    size_t i = (size_t)gid * 8;
    if (i < (size_t)n * D) {
        float4 a = *(const float4*)&x[i];
        float4 b = *(const float4*)&x[i + 4];
        short8 v;
        v[0] = (short)f2bf(a.x); v[1] = (short)f2bf(a.y);
        v[2] = (short)f2bf(a.z); v[3] = (short)f2bf(a.w);
        v[4] = (short)f2bf(b.x); v[5] = (short)f2bf(b.y);
        v[6] = (short)f2bf(b.z); v[7] = (short)f2bf(b.w);
        *(short8*)&xb[i] = v;
    }
    if (gid < 8192) {
        int ct = gid >> 9, rem = gid & 511;
        int ks = rem >> 6, ln = rem & 63;
        int q = ln >> 4, l = ln & 15;
        const float* src = &W[(size_t)(ct * 16 + l) * D + ks * 32 + q * 8];
        float4 c = *(const float4*)src;
        float4 d2 = *(const float4*)(src + 4);
        short8 w;
        w[0] = (short)f2bf(c.x); w[1] = (short)f2bf(c.y);
        w[2] = (short)f2bf(c.z); w[3] = (short)f2bf(c.w);
        w[4] = (short)f2bf(d2.x); w[5] = (short)f2bf(d2.y);
        w[6] = (short)f2bf(d2.z); w[7] = (short)f2bf(d2.w);
        *(short8*)&Wp[(size_t)gid * 8] = w;
    }
}

// Row-offset scan chunk + degree histogram (256 bins, b = 255-min(deg,255)
// so an ascending scan of bins yields DESCENDING degree order).
__global__ void k_scan1(const int* __restrict__ counts, int* __restrict__ row_start,
                        int* __restrict__ blk_sums, int* __restrict__ dhist, int n) {
    __shared__ int sd[256];
    __shared__ int dh[256];
    int tid = threadIdx.x;
    dh[tid] = 0;
    int base = blockIdx.x * SCAN_CHUNK + tid * 8;
    int v[8];
    int s = 0;
#pragma unroll
    for (int i = 0; i < 8; ++i) {
        int idx = base + i;
        v[i] = (idx < n) ? counts[idx] : 0;
        s += v[i];
    }
    sd[tid] = s;
    __syncthreads();  // also publishes dh zeroing
    for (int off = 1; off < 256; off <<= 1) {
        int t = (tid >= off) ? sd[tid - off] : 0;
        __syncthreads();
        sd[tid] += t;
        __syncthreads();
    }
    int run = sd[tid] - s;
    if (tid == 255) blk_sums[blockIdx.x] = sd[255];
#pragma unroll
    for (int i = 0; i < 8; ++i) {
        int idx = base + i;
        if (idx < n) {
            row_start[idx] = run;
            atomicAdd(&dh[255 - min(v[i], 255)], 1);
        }
        run += v[i];
    }
    __syncthreads();
    if (dh[tid]) atomicAdd(&dhist[tid], dh[tid]);
}

// Chunk-sum scan (thread 0 serial over <=64 chunks) + parallel 256-bin degree
// scan -> dcur (seeded bin cursors for the block-chunk reservations).
__global__ void k_scan2(int* __restrict__ blk_sums, int* __restrict__ row_start,
                        const int* __restrict__ dhist, int* __restrict__ dcur,
                        int nch, int n) {
    __shared__ int sd[64];
    __shared__ int dh[256];
    int tid = threadIdx.x;
    if (tid < nch) sd[tid] = blk_sums[tid];
    dh[tid] = dhist[tid];
    __syncthreads();
    if (tid == 0) {
        int run = 0;
        for (int b = 0; b < nch; ++b) { int t = sd[b]; sd[b] = run; run += t; }
        row_start[n] = run;
    }
    __syncthreads();
    if (tid < nch) blk_sums[tid] = sd[tid];
    int own = dh[tid];
    for (int off = 1; off < 256; off <<= 1) {
        int t = (tid >= off) ? dh[tid - off] : 0;
        __syncthreads();
        dh[tid] += t;
        __syncthreads();
    }
    dcur[tid] = dh[tid] - own;  // exclusive bin start
}

// Finalize row_start and seed cursor = row_start (scatter then needs only the
// atomicAdd — no random row_start reads).
__global__ void k_scan3(int* __restrict__ row_start, const int* __restrict__ blk_sums,
                        int* __restrict__ cursor, int n) {
    int i = blockIdx.x * blockDim.x + threadIdx.x;
    if (i < n) {
        int v = row_start[i] + blk_sums[i >> 11];
        row_start[i] = v;
        cursor[i] = v;
    }
}

// Fused: (a) first nch blocks do the block-aggregated degree-sort scatter
// (LDS hist + one global atomicAdd per (block,bin)); (b) all blocks do the
// CSR edge scatter via pre-seeded cursor.
__global__ __launch_bounds__(256) void k_edges(
    const int* __restrict__ erow, const int* __restrict__ ecol,
    const float* __restrict__ eval, int* __restrict__ cursor,
    int2* __restrict__ sedge, const int* __restrict__ counts,
    int* __restrict__ dcur, int* __restrict__ perm, int e, int n) {
    const int tid = threadIdx.x;
    const int nch = (n + SCAN_CHUNK - 1) / SCAN_CHUNK;
    if (blockIdx.x < nch) {  // block-uniform branch
        __shared__ int lh[256];
        __shared__ int lbase[256];
        lh[tid] = 0;
        __syncthreads();
        const int base = blockIdx.x * SCAN_CHUNK + tid * 8;
        int b[8], rank[8];
#pragma unroll
        for (int i = 0; i < 8; ++i) {
            int idx = base + i;
            if (idx < n) {
                b[i] = 255 - min(counts[idx], 255);
                rank[i] = atomicAdd(&lh[b[i]], 1);
            }
        }
        __syncthreads();
        if (lh[tid]) lbase[tid] = atomicAdd(&dcur[tid], lh[tid]);
        __syncthreads();
#pragma unroll
        for (int i = 0; i < 8; ++i) {
            int idx = base + i;
            if (idx < n) perm[lbase[b[i]] + rank[i]] = idx;
        }
    }
    int i = blockIdx.x * blockDim.x + tid;
    if (i < e) {
        int r = erow[i];
        int p = atomicAdd(&cursor[r], 1);
        sedge[p] = make_int2(ecol[i], __float_as_int(eval[i]));
    }
}

// Fused gather + GEMM. Gather: each wave owns 8 perm'd (degree-matched) nodes
// in parallel, fp32 reg acc, bf16 x rows (512B/edge). Rows land in LDS
// (stride 264 bf16 -> 2-way banks). GEMM: 4 waves split 2 row-tiles x
// (2x8 col-tiles); A-frags ds_read_b128 from LDS, B-frags are 1KB coalesced
// loads from fragment-ordered Wp (L2-hot, 128KB). C/D: col=lane&15,
// row=quad*4+reg (m89-verified). Out rows written per perm (scattered 1KB).
__global__ __launch_bounds__(256) void k_gg(
    const unsigned short* __restrict__ xb, const int2* __restrict__ sedge,
    const int* __restrict__ row_start, const int* __restrict__ perm,
    const unsigned short* __restrict__ Wp, const float* __restrict__ bias,
    float* __restrict__ out, int n) {
    __shared__ __align__(16) unsigned short aggl[32][264];  // 16.5KB
    __shared__ int pnl[32];
    const int tid = threadIdx.x;
    const int lane = tid & 63;
    const int wv = tid >> 6;
    const int base = blockIdx.x * NPB + wv * 8;

    int pn[8], ebeg[8], eend[8];
    int maxd = 0;
#pragma unroll
    for (int j = 0; j < 8; ++j) {
        pn[j] = perm[min(base + j, n - 1)];
        ebeg[j] = row_start[pn[j]];
        eend[j] = row_start[pn[j] + 1];
        maxd = max(maxd, eend[j] - ebeg[j]);
    }
    if (lane == 0) {
#pragma unroll
        for (int j = 0; j < 8; ++j) pnl[wv * 8 + j] = pn[j];
    }
    float4 acc[8];
#pragma unroll
    for (int j = 0; j < 8; ++j) acc[j] = make_float4(0.f, 0.f, 0.f, 0.f);

    for (int it = 0; it < maxd; ++it) {
        int2 ev[8];
        ushort4 xv[8];
#pragma unroll
        for (int j = 0; j < 8; ++j) {
            int e = ebeg[j] + it;
            int ec = max(min(e, eend[j] - 1), 0);  // clamped: always valid
            ev[j] = sedge[ec];
        }
#pragma unroll
        for (int j = 0; j < 8; ++j) {
            // 8B/lane, 512B/wave coalesced bf16 row slice
            xv[j] = *(const ushort4*)&xb[(size_t)ev[j].x * D + lane * 4];
        }
#pragma unroll
        for (int j = 0; j < 8; ++j) {
            float v = (ebeg[j] + it < eend[j]) ? __int_as_float(ev[j].y) : 0.f;
            acc[j].x += v * bf2f(xv[j].x);
            acc[j].y += v * bf2f(xv[j].y);
            acc[j].z += v * bf2f(xv[j].z);
            acc[j].w += v * bf2f(xv[j].w);
        }
    }
#pragma unroll
    for (int j = 0; j < 8; ++j) {
        ushort4 u;
        u.x = f2bf(acc[j].x);
        u.y = f2bf(acc[j].y);
        u.z = f2bf(acc[j].z);
        u.w = f2bf(acc[j].w);
        *(ushort4*)&aggl[wv * 8 + j][lane * 4] = u;  // 2-way banks (stride 528B)
    }
    __syncthreads();

    // ---- GEMM phase: out[32 x 256] = aggl @ W^T + b ----
    const int q = lane >> 4, l = lane & 15;
    const int rt = wv >> 1;          // row-tile (16 rows each)
    const int cb = (wv & 1) * 8;     // col-tile base (8 tiles of 16)
    floatx4 gac[8];
#pragma unroll
    for (int i = 0; i < 8; ++i) gac[i] = (floatx4){0.f, 0.f, 0.f, 0.f};
#pragma unroll
    for (int ks = 0; ks < 8; ++ks) {
        short8 a = *(const short8*)&aggl[rt * 16 + l][ks * 32 + q * 8];
#pragma unroll
        for (int i = 0; i < 8; ++i) {
            short8 b = *(const short8*)&Wp[(size_t)(((cb + i) * 8 + ks) * 64 + lane) * 8];
            gac[i] = __builtin_amdgcn_mfma_f32_16x16x32_bf16(a, b, gac[i], 0, 0, 0);
        }
    }
#pragma unroll
    for (int i = 0; i < 8; ++i) {
        int o = (cb + i) * 16 + l;
        float bv = bias[o];
#pragma unroll
        for (int r = 0; r < 4; ++r) {
            int row = rt * 16 + q * 4 + r;
            if (base - wv * 8 + row < n)  // block-base + row guard (exact here)
                out[(size_t)pnl[row] * D + o] = gac[i][r] + bv;
        }
    }
}

extern "C" void kernel_launch(void* const* d_in, const int* in_sizes, int n_in,
                              void* d_out, int out_size, void* d_ws, size_t ws_size,
                              hipStream_t stream) {
    const float* x    = (const float*)d_in[0];
    const int*   erow = (const int*)d_in[1];
    const int*   ecol = (const int*)d_in[2];
    const float* eval = (const float*)d_in[3];
    const float* W    = (const float*)d_in[4];
    const float* bias = (const float*)d_in[5];
    float* out = (float*)d_out;

    const int n = in_sizes[0] / D;  // 100000
    const int e = in_sizes[1];      // 3200000

    // ws: counts[n] | dhist[256] | dcur[256] | cursor[n] | blk_sums[64]
    //     | row_start[n+1] | perm[n] | sedge[e] int2 | Wp[65536] u16
    //     | xb[n*256] u16
    int* counts    = (int*)d_ws;
    int* dhist     = counts + n;
    int* dcur      = dhist + 256;
    int* cursor    = dcur + 256;
    int* blk_sums  = cursor + n;
    int* row_start = blk_sums + 64;
    int* perm      = row_start + n + 1;
    int2* sedge    = (int2*)(((uintptr_t)(perm + n) + 15) & ~(uintptr_t)15);
    unsigned short* Wp = (unsigned short*)(sedge + e);
    unsigned short* xb = Wp + 65536;

    // zero: counts + dhist (dcur/cursor/blk_sums fully written by scans)
    hipMemsetAsync(counts, 0, (size_t)(n + 256) * sizeof(int), stream);

    const int nch = (n + SCAN_CHUNK - 1) / SCAN_CHUNK;  // 49
    const int prep_grid = max((e + 255) / 256, (n * D / 8 + 255) / 256);

    k_prep<<<prep_grid, 256, 0, stream>>>(erow, counts, x, xb, W, Wp, e, n);
    k_scan1<<<nch, 256, 0, stream>>>(counts, row_start, blk_sums, dhist, n);
    k_scan2<<<1, 256, 0, stream>>>(blk_sums, row_start, dhist, dcur, nch, n);
    k_scan3<<<(n + 255) / 256, 256, 0, stream>>>(row_start, blk_sums, cursor, n);
    k_edges<<<(e + 255) / 256, 256, 0, stream>>>(erow, ecol, eval, cursor, sedge,
                                                 counts, dcur, perm, e, n);
    k_gg<<<(n + NPB - 1) / NPB, 256, 0, stream>>>(xb, sedge, row_start, perm,
                                                  Wp, bias, out, n);
}

// Round 5
// 698.683 us; speedup vs baseline: 1.5466x; 1.2405x over previous
//
#include <hip/hip_runtime.h>
#include <cstdint>
#include <cstddef>

// GraphConvolution: out = (A_sparse @ x) @ W^T + b   (N=100000, E=3.2M, D=256)
// Pipeline (9 launches): memset -> prep(hist+bucket-bins+castX+castWp)
//   -> scan1 -> scan2 -> scan3 -> off(bucket offsets + deg-sort perm)
//   -> stage(LDS-reordered bucket write) -> csr(bucket-local exact scatter)
//   -> gather+GEMM fused (k_gg, UNCHANGED from R4 as control).
// NOTE: never use the 2nd __launch_bounds__ arg on gather — caps VGPRs ~84,
// forces GBs of scratch spill.
// R4: bf16 x halves per-edge bytes — gather byte-bound. 495->310us.
// R5: degree-sorted node assignment removes max-of-8 padding (310->278).
// R6: block-aggregated counting sort (hot-atomic fix; R2 lesson: same-address
//     global atomics ~36ns serialized — never exceed ~100 depth).
// R7: fused gather+GEMM via LDS agg tile + fragment-ordered Wp. k_gg=330us.
// R8(this): the hidden remainder (~537us) is dominated by the CSR edge
//   scatter's random 8B write-allocate traffic (line reuse distance = whole
//   edge stream -> ~8x amplification). Two-level bucketed scatter: exact
//   per-chunk offsets via scan (no hot atomics), LDS-reordered coalesced
//   staging runs, then per-bucket single-CU L2-resident exact scatter.
#define D 256
#define NPB 32
#define SCAN_CHUNK 2048
#define BROWS 512      // rows per bucket
#define NBUCK 196      // ceil(100000/512)
#define CHUNK_E 4096   // edges per staging chunk

typedef __attribute__((ext_vector_type(8))) short short8;
typedef __attribute__((ext_vector_type(4))) float floatx4;

__device__ __forceinline__ unsigned short f2bf(float f) {
    union { float f; unsigned int u; } cv; cv.f = f;
    unsigned int u = cv.u;
    unsigned int r = (u + 0x7fffu + ((u >> 16) & 1u)) >> 16;  // RNE
    return (unsigned short)r;
}

__device__ __forceinline__ float bf2f(unsigned short s) {
    union { unsigned int u; float f; } cv;
    cv.u = ((unsigned int)s) << 16;
    return cv.f;
}

// hist + per-chunk bucket bins + castX + castWp.
// Wp layout: flat j = ((ct*8 + ks)*64 + q*16 + l), Wp[j*8..+8] =
//   bf16(W[ct*16 + l][ks*32 + q*8 .. +8])  -> B-frag load is 1KB coalesced.
__global__ void k_prep(const int* __restrict__ erow, int* __restrict__ counts,
                       int* __restrict__ blkbins,
                       const float* __restrict__ x, unsigned short* __restrict__ xb,
                       const float* __restrict__ W, unsigned short* __restrict__ Wp,
                       int e, int n) {
    __shared__ int lb[NBUCK];
    const int tid = threadIdx.x;
    if (tid < NBUCK) lb[tid] = 0;
    __syncthreads();
    int gid = blockIdx.x * blockDim.x + tid;
    if (gid < e) {
        int r = erow[gid];
        atomicAdd(&counts[r], 1);
        atomicAdd(&lb[r >> 9], 1);
    }
    size_t i = (size_t)gid * 8;
    if (i < (size_t)n * D) {
        float4 a = *(const float4*)&x[i];
        float4 b = *(const float4*)&x[i + 4];
        short8 v;
        v[0] = (short)f2bf(a.x); v[1] = (short)f2bf(a.y);
        v[2] = (short)f2bf(a.z); v[3] = (short)f2bf(a.w);
        v[4] = (short)f2bf(b.x); v[5] = (short)f2bf(b.y);
        v[6] = (short)f2bf(b.z); v[7] = (short)f2bf(b.w);
        *(short8*)&xb[i] = v;
    }
    if (gid < 8192) {
        int ct = gid >> 9, rem = gid & 511;
        int ks = rem >> 6, ln = rem & 63;
        int q = ln >> 4, l = ln & 15;
        const float* src = &W[(size_t)(ct * 16 + l) * D + ks * 32 + q * 8];
        float4 c = *(const float4*)src;
        float4 d2 = *(const float4*)(src + 4);
        short8 w;
        w[0] = (short)f2bf(c.x); w[1] = (short)f2bf(c.y);
        w[2] = (short)f2bf(c.z); w[3] = (short)f2bf(c.w);
        w[4] = (short)f2bf(d2.x); w[5] = (short)f2bf(d2.y);
        w[6] = (short)f2bf(d2.z); w[7] = (short)f2bf(d2.w);
        *(short8*)&Wp[(size_t)gid * 8] = w;
    }
    __syncthreads();
    if (tid < NBUCK && lb[tid])
        atomicAdd(&blkbins[(blockIdx.x >> 4) * NBUCK + tid], lb[tid]);
}

// Row-offset scan chunk + degree histogram (256 bins, b = 255-min(deg,255)
// so an ascending scan of bins yields DESCENDING degree order).
__global__ void k_scan1(const int* __restrict__ counts, int* __restrict__ row_start,
                        int* __restrict__ blk_sums, int* __restrict__ dhist, int n) {
    __shared__ int sd[256];
    __shared__ int dh[256];
    int tid = threadIdx.x;
    dh[tid] = 0;
    int base = blockIdx.x * SCAN_CHUNK + tid * 8;
    int v[8];
    int s = 0;
#pragma unroll
    for (int i = 0; i < 8; ++i) {
        int idx = base + i;
        v[i] = (idx < n) ? counts[idx] : 0;
        s += v[i];
    }
    sd[tid] = s;
    __syncthreads();
    for (int off = 1; off < 256; off <<= 1) {
        int t = (tid >= off) ? sd[tid - off] : 0;
        __syncthreads();
        sd[tid] += t;
        __syncthreads();
    }
    int run = sd[tid] - s;
    if (tid == 255) blk_sums[blockIdx.x] = sd[255];
#pragma unroll
    for (int i = 0; i < 8; ++i) {
        int idx = base + i;
        if (idx < n) {
            row_start[idx] = run;
            atomicAdd(&dh[255 - min(v[i], 255)], 1);
        }
        run += v[i];
    }
    __syncthreads();
    if (dh[tid]) atomicAdd(&dhist[tid], dh[tid]);
}

// Chunk-sum scan + parallel 256-bin degree scan -> dcur.
__global__ void k_scan2(int* __restrict__ blk_sums, int* __restrict__ row_start,
                        const int* __restrict__ dhist, int* __restrict__ dcur,
                        int nch, int n) {
    __shared__ int sd[64];
    __shared__ int dh[256];
    int tid = threadIdx.x;
    if (tid < nch) sd[tid] = blk_sums[tid];
    dh[tid] = dhist[tid];
    __syncthreads();
    if (tid == 0) {
        int run = 0;
        for (int b = 0; b < nch; ++b) { int t = sd[b]; sd[b] = run; run += t; }
        row_start[n] = run;
    }
    __syncthreads();
    if (tid < nch) blk_sums[tid] = sd[tid];
    int own = dh[tid];
    for (int off = 1; off < 256; off <<= 1) {
        int t = (tid >= off) ? dh[tid - off] : 0;
        __syncthreads();
        dh[tid] += t;
        __syncthreads();
    }
    dcur[tid] = dh[tid] - own;  // exclusive bin start
}

// Finalize row_start.
__global__ void k_scan3(int* __restrict__ row_start, const int* __restrict__ blk_sums, int n) {
    int i = blockIdx.x * blockDim.x + threadIdx.x;
    if (i < n) row_start[i] += blk_sums[i >> 11];
}

// Per-bucket exclusive scan over chunk bins -> exact staging offsets
// (seeded at row_start[b*BROWS], so staged indexing == final CSR indexing).
// Blocks 0..48 also build the descending-degree perm (block-aggregated).
__global__ __launch_bounds__(256) void k_off(
    const int* __restrict__ blkbins, int* __restrict__ blkoff,
    const int* __restrict__ row_start, const int* __restrict__ counts,
    int* __restrict__ dcur, int* __restrict__ perm, int nchunk, int n) {
    __shared__ int sd[256];
    __shared__ int lh[256];
    __shared__ int lbase[256];
    const int tid = threadIdx.x;
    const int nch = (n + SCAN_CHUNK - 1) / SCAN_CHUNK;
    if (blockIdx.x < (unsigned)nch) {  // deg-sort duty
        lh[tid] = 0;
        __syncthreads();
        const int base = blockIdx.x * SCAN_CHUNK + tid * 8;
        int b[8], rank[8];
#pragma unroll
        for (int i = 0; i < 8; ++i) {
            int idx = base + i;
            if (idx < n) {
                b[i] = 255 - min(counts[idx], 255);
                rank[i] = atomicAdd(&lh[b[i]], 1);
            }
        }
        __syncthreads();
        if (lh[tid]) lbase[tid] = atomicAdd(&dcur[tid], lh[tid]);
        __syncthreads();
#pragma unroll
        for (int i = 0; i < 8; ++i) {
            int idx = base + i;
            if (idx < n) perm[lbase[b[i]] + rank[i]] = idx;
        }
        __syncthreads();
    }
    // bucket-offset scan
    const int bk = blockIdx.x;
    int carry = row_start[bk * BROWS];
    for (int c0 = 0; c0 < nchunk; c0 += 256) {
        int c = c0 + tid;
        int v = (c < nchunk) ? blkbins[c * NBUCK + bk] : 0;
        sd[tid] = v;
        __syncthreads();
        for (int off = 1; off < 256; off <<= 1) {
            int t = (tid >= off) ? sd[tid - off] : 0;
            __syncthreads();
            sd[tid] += t;
            __syncthreads();
        }
        if (c < nchunk) blkoff[c * NBUCK + bk] = carry + sd[tid] - v;
        int tot = sd[255];
        __syncthreads();
        carry += tot;
    }
}

// Stage: each 4096-edge chunk reorders its edges bucket-contiguously through
// LDS, then writes coalesced runs (avg ~21 edges = 168B per (chunk,bucket))
// to exact precomputed offsets. Payload packs (localrow<<17)|col + val.
__global__ __launch_bounds__(256) void k_stage(
    const int* __restrict__ erow, const int* __restrict__ ecol,
    const float* __restrict__ eval, const int* __restrict__ blkoff,
    int2* __restrict__ staged, int e) {
    __shared__ int lb[NBUCK];
    __shared__ int gb[NBUCK];
    __shared__ int sc[256];
    __shared__ unsigned char bid[CHUNK_E];
    __shared__ int2 ebuf[CHUNK_E];  // 32KB
    const int tid = threadIdx.x;
    if (tid < NBUCK) lb[tid] = 0;
    __syncthreads();
    const int ebase = blockIdx.x * CHUNK_E;
    int bk[16], rk[16];
#pragma unroll
    for (int i = 0; i < 16; ++i) {
        int idx = ebase + i * 256 + tid;
        bk[i] = -1;
        if (idx < e) {
            bk[i] = erow[idx] >> 9;
            rk[i] = atomicAdd(&lb[bk[i]], 1);
        }
    }
    __syncthreads();
    int v = (tid < NBUCK) ? lb[tid] : 0;
    sc[tid] = v;
    __syncthreads();
    for (int off = 1; off < 256; off <<= 1) {
        int t = (tid >= off) ? sc[tid - off] : 0;
        __syncthreads();
        sc[tid] += t;
        __syncthreads();
    }
    int loff = sc[tid] - v;  // exclusive
    if (tid < NBUCK) {
        lb[tid] = loff;
        gb[tid] = blkoff[blockIdx.x * NBUCK + tid] - loff;  // dst = gb[b] + slot
    }
    __syncthreads();
#pragma unroll
    for (int i = 0; i < 16; ++i) {
        if (bk[i] >= 0) {
            int idx = ebase + i * 256 + tid;
            int slot = lb[bk[i]] + rk[i];
            int r = erow[idx];
            ebuf[slot] = make_int2(((r & (BROWS - 1)) << 17) | ecol[idx],
                                   __float_as_int(eval[idx]));
            bid[slot] = (unsigned char)bk[i];
        }
    }
    __syncthreads();
    const int cnt = min(e - ebase, CHUNK_E);
#pragma unroll
    for (int i = 0; i < 16; ++i) {
        int s = i * 256 + tid;
        if (s < cnt) staged[gb[bid[s]] + s] = ebuf[s];
    }
}

// Exact CSR scatter, one block per bucket: LDS row cursors; reads staged
// coalesced, writes sedge inside a ~128KB single-CU window (L2-resident RMW,
// no cross-XCD dirty-line sharing).
__global__ __launch_bounds__(256) void k_csr(
    const int2* __restrict__ staged, const int* __restrict__ row_start,
    int2* __restrict__ sedge, int n) {
    __shared__ int lcur[BROWS];
    const int b = blockIdx.x, tid = threadIdx.x;
    const int r0 = b * BROWS;
    const int rend = min(r0 + BROWS, n);
    for (int i = tid; i < rend - r0; i += 256) lcur[i] = row_start[r0 + i];
    __syncthreads();
    const int beg = row_start[r0];
    const int end = row_start[rend];
    for (int idx = beg + tid; idx < end; idx += 256) {
        int2 sv = staged[idx];
        int lr = ((unsigned)sv.x) >> 17;
        int p = atomicAdd(&lcur[lr], 1);
        sedge[p] = make_int2(sv.x & 0x1FFFF, sv.y);
    }
}

// Fused gather + GEMM — UNCHANGED from R4 (control).
__global__ __launch_bounds__(256) void k_gg(
    const unsigned short* __restrict__ xb, const int2* __restrict__ sedge,
    const int* __restrict__ row_start, const int* __restrict__ perm,
    const unsigned short* __restrict__ Wp, const float* __restrict__ bias,
    float* __restrict__ out, int n) {
    __shared__ __align__(16) unsigned short aggl[32][264];  // 16.5KB
    __shared__ int pnl[32];
    const int tid = threadIdx.x;
    const int lane = tid & 63;
    const int wv = tid >> 6;
    const int base = blockIdx.x * NPB + wv * 8;

    int pn[8], ebeg[8], eend[8];
    int maxd = 0;
#pragma unroll
    for (int j = 0; j < 8; ++j) {
        pn[j] = perm[min(base + j, n - 1)];
        ebeg[j] = row_start[pn[j]];
        eend[j] = row_start[pn[j] + 1];
        maxd = max(maxd, eend[j] - ebeg[j]);
    }
    if (lane == 0) {
#pragma unroll
        for (int j = 0; j < 8; ++j) pnl[wv * 8 + j] = pn[j];
    }
    float4 acc[8];
#pragma unroll
    for (int j = 0; j < 8; ++j) acc[j] = make_float4(0.f, 0.f, 0.f, 0.f);

    for (int it = 0; it < maxd; ++it) {
        int2 ev[8];
        ushort4 xv[8];
#pragma unroll
        for (int j = 0; j < 8; ++j) {
            int e = ebeg[j] + it;
            int ec = max(min(e, eend[j] - 1), 0);  // clamped: always valid
            ev[j] = sedge[ec];
        }
#pragma unroll
        for (int j = 0; j < 8; ++j) {
            xv[j] = *(const ushort4*)&xb[(size_t)ev[j].x * D + lane * 4];
        }
#pragma unroll
        for (int j = 0; j < 8; ++j) {
            float v = (ebeg[j] + it < eend[j]) ? __int_as_float(ev[j].y) : 0.f;
            acc[j].x += v * bf2f(xv[j].x);
            acc[j].y += v * bf2f(xv[j].y);
            acc[j].z += v * bf2f(xv[j].z);
            acc[j].w += v * bf2f(xv[j].w);
        }
    }
#pragma unroll
    for (int j = 0; j < 8; ++j) {
        ushort4 u;
        u.x = f2bf(acc[j].x);
        u.y = f2bf(acc[j].y);
        u.z = f2bf(acc[j].z);
        u.w = f2bf(acc[j].w);
        *(ushort4*)&aggl[wv * 8 + j][lane * 4] = u;
    }
    __syncthreads();

    const int q = lane >> 4, l = lane & 15;
    const int rt = wv >> 1;
    const int cb = (wv & 1) * 8;
    floatx4 gac[8];
#pragma unroll
    for (int i = 0; i < 8; ++i) gac[i] = (floatx4){0.f, 0.f, 0.f, 0.f};
#pragma unroll
    for (int ks = 0; ks < 8; ++ks) {
        short8 a = *(const short8*)&aggl[rt * 16 + l][ks * 32 + q * 8];
#pragma unroll
        for (int i = 0; i < 8; ++i) {
            short8 b = *(const short8*)&Wp[(size_t)(((cb + i) * 8 + ks) * 64 + lane) * 8];
            gac[i] = __builtin_amdgcn_mfma_f32_16x16x32_bf16(a, b, gac[i], 0, 0, 0);
        }
    }
#pragma unroll
    for (int i = 0; i < 8; ++i) {
        int o = (cb + i) * 16 + l;
        float bv = bias[o];
#pragma unroll
        for (int r = 0; r < 4; ++r) {
            int row = rt * 16 + q * 4 + r;
            if (base - wv * 8 + row < n)
                out[(size_t)pnl[row] * D + o] = gac[i][r] + bv;
        }
    }
}

extern "C" void kernel_launch(void* const* d_in, const int* in_sizes, int n_in,
                              void* d_out, int out_size, void* d_ws, size_t ws_size,
                              hipStream_t stream) {
    const float* x    = (const float*)d_in[0];
    const int*   erow = (const int*)d_in[1];
    const int*   ecol = (const int*)d_in[2];
    const float* eval = (const float*)d_in[3];
    const float* W    = (const float*)d_in[4];
    const float* bias = (const float*)d_in[5];
    float* out = (float*)d_out;

    const int n = in_sizes[0] / D;  // 100000
    const int e = in_sizes[1];      // 3200000
    const int nchunk = (e + CHUNK_E - 1) / CHUNK_E;  // 782

    // ws: counts[n] | dhist[256] | blkbins[nchunk*NBUCK] | dcur[256]
    //     | blk_sums[64] | row_start[n+1] | perm[n] | blkoff[nchunk*NBUCK]
    //     | staged[e] int2 | sedge[e] int2 | Wp[65536] u16 | xb[n*256] u16
    int* counts    = (int*)d_ws;
    int* dhist     = counts + n;
    int* blkbins   = dhist + 256;
    int* dcur      = blkbins + (size_t)nchunk * NBUCK;
    int* blk_sums  = dcur + 256;
    int* row_start = blk_sums + 64;
    int* perm      = row_start + n + 1;
    int* blkoff    = perm + n;
    int2* staged   = (int2*)(((uintptr_t)(blkoff + (size_t)nchunk * NBUCK) + 15) & ~(uintptr_t)15);
    int2* sedge    = staged + e;
    unsigned short* Wp = (unsigned short*)(sedge + e);
    unsigned short* xb = Wp + 65536;

    // zero: counts + dhist + blkbins (contiguous)
    hipMemsetAsync(counts, 0, ((size_t)n + 256 + (size_t)nchunk * NBUCK) * sizeof(int), stream);

    const int nch = (n + SCAN_CHUNK - 1) / SCAN_CHUNK;  // 49

    k_prep<<<12500, 256, 0, stream>>>(erow, counts, blkbins, x, xb, W, Wp, e, n);
    k_scan1<<<nch, 256, 0, stream>>>(counts, row_start, blk_sums, dhist, n);
    k_scan2<<<1, 256, 0, stream>>>(blk_sums, row_start, dhist, dcur, nch, n);
    k_scan3<<<(n + 255) / 256, 256, 0, stream>>>(row_start, blk_sums, n);
    k_off<<<NBUCK, 256, 0, stream>>>(blkbins, blkoff, row_start, counts, dcur, perm, nchunk, n);
    k_stage<<<nchunk, 256, 0, stream>>>(erow, ecol, eval, blkoff, staged, e);
    k_csr<<<NBUCK, 256, 0, stream>>>(staged, row_start, sedge, n);
    k_gg<<<(n + NPB - 1) / NPB, 256, 0, stream>>>(xb, sedge, row_start, perm,
                                                  Wp, bias, out, n);
}

// Round 6
// 614.766 us; speedup vs baseline: 1.7577x; 1.1365x over previous
//
#include <hip/hip_runtime.h>
#include <cstdint>
#include <cstddef>

// GraphConvolution: out = (A_sparse @ x) @ W^T + b   (N=100000, E=3.2M, D=256)
// Pipeline (8 launches): memset -> prep(chunk-bucket-bins + castX + castWp)
//   -> off(per-bucket chunk scans) -> bscan(bucket starts) -> stage(LDS
//   bucket reorder) -> csr(LDS hist+scan -> row_start/degrees + exact
//   scatter) -> perm(deg-sort) -> gather+GEMM fused (k_gg, control).
// NOTE: never use the 2nd __launch_bounds__ arg on gather — caps VGPRs ~84,
// forces GBs of scratch spill.
// R4: bf16 x halves per-edge bytes — gather byte-bound. 495->310us.
// R5: degree-sorted node assignment removes max-of-8 padding (310->278).
// R6: block-aggregated counting sort (R2 lesson: hot same-address global
//     atomics serialize; never exceed ~100 depth per address).
// R7: fused gather+GEMM via LDS agg tile + fragment-ordered Wp. k_gg=330us.
// R8: bucketed two-level scatter kills write-allocate amplification. 867->699.
// R9(this): kill the 3.2M random global atomicAdds of the degree histogram —
//   degrees are recomputed for free inside k_csr from bucket-local edges via
//   LDS hist+scan (which also emits row_start, replacing scan1/2/3).
#define D 256
#define NPB 32
#define BROWS 512      // rows per bucket
#define NBUCK 196      // ceil(100000/512)
#define CHUNK_E 4096   // edges per staging chunk

typedef __attribute__((ext_vector_type(8))) short short8;
typedef __attribute__((ext_vector_type(4))) float floatx4;

__device__ __forceinline__ unsigned short f2bf(float f) {
    union { float f; unsigned int u; } cv; cv.f = f;
    unsigned int u = cv.u;
    unsigned int r = (u + 0x7fffu + ((u >> 16) & 1u)) >> 16;  // RNE
    return (unsigned short)r;
}

__device__ __forceinline__ float bf2f(unsigned short s) {
    union { unsigned int u; float f; } cv;
    cv.u = ((unsigned int)s) << 16;
    return cv.f;
}

// Per-chunk bucket bins (LDS-aggregated, avg depth 1.3) + castX + castWp.
// NO per-row global atomics.
// Wp layout: flat j = ((ct*8 + ks)*64 + q*16 + l), Wp[j*8..+8] =
//   bf16(W[ct*16 + l][ks*32 + q*8 .. +8])  -> B-frag load is 1KB coalesced.
__global__ void k_prep(const int* __restrict__ erow, int* __restrict__ blkbins,
                       const float* __restrict__ x, unsigned short* __restrict__ xb,
                       const float* __restrict__ W, unsigned short* __restrict__ Wp,
                       int e, int n) {
    __shared__ int lb[NBUCK];
    const int tid = threadIdx.x;
    if (tid < NBUCK) lb[tid] = 0;
    __syncthreads();
    int gid = blockIdx.x * blockDim.x + tid;
    if (gid < e) atomicAdd(&lb[erow[gid] >> 9], 1);
    size_t i = (size_t)gid * 8;
    if (i < (size_t)n * D) {
        float4 a = *(const float4*)&x[i];
        float4 b = *(const float4*)&x[i + 4];
        short8 v;
        v[0] = (short)f2bf(a.x); v[1] = (short)f2bf(a.y);
        v[2] = (short)f2bf(a.z); v[3] = (short)f2bf(a.w);
        v[4] = (short)f2bf(b.x); v[5] = (short)f2bf(b.y);
        v[6] = (short)f2bf(b.z); v[7] = (short)f2bf(b.w);
        *(short8*)&xb[i] = v;
    }
    if (gid < 8192) {
        int ct = gid >> 9, rem = gid & 511;
        int ks = rem >> 6, ln = rem & 63;
        int q = ln >> 4, l = ln & 15;
        const float* src = &W[(size_t)(ct * 16 + l) * D + ks * 32 + q * 8];
        float4 c = *(const float4*)src;
        float4 d2 = *(const float4*)(src + 4);
        short8 w;
        w[0] = (short)f2bf(c.x); w[1] = (short)f2bf(c.y);
        w[2] = (short)f2bf(c.z); w[3] = (short)f2bf(c.w);
        w[4] = (short)f2bf(d2.x); w[5] = (short)f2bf(d2.y);
        w[6] = (short)f2bf(d2.z); w[7] = (short)f2bf(d2.w);
        *(short8*)&Wp[(size_t)gid * 8] = w;
    }
    __syncthreads();
    if (tid < NBUCK && lb[tid])
        atomicAdd(&blkbins[(blockIdx.x >> 4) * NBUCK + tid], lb[tid]);
}

// Per-bucket exclusive scan over chunk bins (seeded at 0) -> blkoff; bucket
// total -> btot.
__global__ __launch_bounds__(256) void k_off(
    const int* __restrict__ blkbins, int* __restrict__ blkoff,
    int* __restrict__ btot, int nchunk) {
    __shared__ int sd[256];
    const int tid = threadIdx.x;
    const int bk = blockIdx.x;
    int carry = 0;
    for (int c0 = 0; c0 < nchunk; c0 += 256) {
        int c = c0 + tid;
        int v = (c < nchunk) ? blkbins[c * NBUCK + bk] : 0;
        sd[tid] = v;
        __syncthreads();
        for (int off = 1; off < 256; off <<= 1) {
            int t = (tid >= off) ? sd[tid - off] : 0;
            __syncthreads();
            sd[tid] += t;
            __syncthreads();
        }
        if (c < nchunk) blkoff[c * NBUCK + bk] = carry + sd[tid] - v;
        int tot = sd[255];
        __syncthreads();
        carry += tot;
    }
    if (tid == 0) btot[bk] = carry;
}

// Scan bucket totals -> bstart (exclusive); bstart[NBUCK] = row_start[n] = e.
__global__ void k_bscan(const int* __restrict__ btot, int* __restrict__ bstart,
                        int* __restrict__ row_start, int n) {
    __shared__ int sd[256];
    const int tid = threadIdx.x;
    int v = (tid < NBUCK) ? btot[tid] : 0;
    sd[tid] = v;
    __syncthreads();
    for (int off = 1; off < 256; off <<= 1) {
        int t = (tid >= off) ? sd[tid - off] : 0;
        __syncthreads();
        sd[tid] += t;
        __syncthreads();
    }
    if (tid < NBUCK) bstart[tid] = sd[tid] - v;
    if (tid == 255) {
        bstart[NBUCK] = sd[255];
        row_start[n] = sd[255];
    }
}

// Stage: each 4096-edge chunk reorders its edges bucket-contiguously through
// LDS, then writes coalesced runs to exact precomputed offsets.
// Payload packs (localrow<<17)|col + val.
__global__ __launch_bounds__(256) void k_stage(
    const int* __restrict__ erow, const int* __restrict__ ecol,
    const float* __restrict__ eval, const int* __restrict__ blkoff,
    const int* __restrict__ bstart, int2* __restrict__ staged, int e) {
    __shared__ int lb[NBUCK];
    __shared__ int gb[NBUCK];
    __shared__ int sc[256];
    __shared__ unsigned char bid[CHUNK_E];
    __shared__ int2 ebuf[CHUNK_E];  // 32KB
    const int tid = threadIdx.x;
    if (tid < NBUCK) lb[tid] = 0;
    __syncthreads();
    const int ebase = blockIdx.x * CHUNK_E;
    int bk[16], rk[16];
#pragma unroll
    for (int i = 0; i < 16; ++i) {
        int idx = ebase + i * 256 + tid;
        bk[i] = -1;
        if (idx < e) {
            bk[i] = erow[idx] >> 9;
            rk[i] = atomicAdd(&lb[bk[i]], 1);
        }
    }
    __syncthreads();
    int v = (tid < NBUCK) ? lb[tid] : 0;
    sc[tid] = v;
    __syncthreads();
    for (int off = 1; off < 256; off <<= 1) {
        int t = (tid >= off) ? sc[tid - off] : 0;
        __syncthreads();
        sc[tid] += t;
        __syncthreads();
    }
    int loff = sc[tid] - v;  // exclusive
    if (tid < NBUCK) {
        lb[tid] = loff;
        gb[tid] = bstart[tid] + blkoff[blockIdx.x * NBUCK + tid] - loff;
    }
    __syncthreads();
#pragma unroll
    for (int i = 0; i < 16; ++i) {
        if (bk[i] >= 0) {
            int idx = ebase + i * 256 + tid;
            int slot = lb[bk[i]] + rk[i];
            int r = erow[idx];
            ebuf[slot] = make_int2(((r & (BROWS - 1)) << 17) | ecol[idx],
                                   __float_as_int(eval[idx]));
            bid[slot] = (unsigned char)bk[i];
        }
    }
    __syncthreads();
    const int cnt = min(e - ebase, CHUNK_E);
#pragma unroll
    for (int i = 0; i < 16; ++i) {
        int s = i * 256 + tid;
        if (s < cnt) staged[gb[bid[s]] + s] = ebuf[s];
    }
}

// One block per bucket: (A) LDS 512-row hist + scan -> row_start, degrees
// (counts), block-aggregated degree-bin hist; (B) exact CSR scatter via LDS
// cursors inside a ~128KB L2-resident window. No per-row global atomics.
__global__ __launch_bounds__(256) void k_csr(
    const int2* __restrict__ staged, const int* __restrict__ bstart,
    int* __restrict__ row_start, int* __restrict__ counts,
    int* __restrict__ dhist, int2* __restrict__ sedge, int n) {
    __shared__ int h[BROWS];
    __shared__ int sc[256];
    __shared__ int dh[256];
    const int b = blockIdx.x, tid = threadIdx.x;
    const int r0 = b * BROWS;
    h[tid] = 0; h[tid + 256] = 0; dh[tid] = 0;
    __syncthreads();
    const int beg = bstart[b];
    const int end = bstart[b + 1];
    for (int idx = beg + tid; idx < end; idx += 256) {
        int lr = ((unsigned)staged[idx].x) >> 17;
        atomicAdd(&h[lr], 1);
    }
    __syncthreads();
    int a0 = h[tid], a1 = h[tid + 256];
    // scan lower 256
    sc[tid] = a0;
    __syncthreads();
    for (int off = 1; off < 256; off <<= 1) {
        int t = (tid >= off) ? sc[tid - off] : 0;
        __syncthreads();
        sc[tid] += t;
        __syncthreads();
    }
    int incl0 = sc[tid];
    int tot0 = sc[255];
    __syncthreads();
    // scan upper 256
    sc[tid] = a1;
    __syncthreads();
    for (int off = 1; off < 256; off <<= 1) {
        int t = (tid >= off) ? sc[tid - off] : 0;
        __syncthreads();
        sc[tid] += t;
        __syncthreads();
    }
    int incl1 = sc[tid];
    __syncthreads();
    int cur0 = beg + incl0 - a0;
    int cur1 = beg + tot0 + incl1 - a1;
    h[tid] = cur0;
    h[tid + 256] = cur1;
    if (r0 + tid < n) {
        row_start[r0 + tid] = cur0;
        counts[r0 + tid] = a0;
        atomicAdd(&dh[255 - min(a0, 255)], 1);
    }
    if (r0 + 256 + tid < n) {
        row_start[r0 + 256 + tid] = cur1;
        counts[r0 + 256 + tid] = a1;
        atomicAdd(&dh[255 - min(a1, 255)], 1);
    }
    __syncthreads();
    if (dh[tid]) atomicAdd(&dhist[tid], dh[tid]);
    // Phase B: exact scatter
    for (int idx = beg + tid; idx < end; idx += 256) {
        int2 sv = staged[idx];
        int lr = ((unsigned)sv.x) >> 17;
        int p = atomicAdd(&h[lr], 1);
        sedge[p] = make_int2(sv.x & 0x1FFFF, sv.y);
    }
}

// Build descending-degree perm. Each block redundantly scans dhist in LDS for
// bin starts, then block-aggregated reservation (1 global atomic per
// (block,bin) — never hot).
__global__ __launch_bounds__(256) void k_perm(
    const int* __restrict__ counts, const int* __restrict__ dhist,
    int* __restrict__ dcur, int* __restrict__ perm, int n) {
    __shared__ int st[256];
    __shared__ int lh[256];
    __shared__ int lbase[256];
    const int tid = threadIdx.x;
    lh[tid] = 0;
    int dv = dhist[tid];
    st[tid] = dv;
    __syncthreads();
    for (int off = 1; off < 256; off <<= 1) {
        int t = (tid >= off) ? st[tid - off] : 0;
        __syncthreads();
        st[tid] += t;
        __syncthreads();
    }
    int start = st[tid] - dv;  // exclusive bin start
    const int base = blockIdx.x * 2048 + tid * 8;
    int bkt[8], rank[8];
#pragma unroll
    for (int i = 0; i < 8; ++i) {
        int idx = base + i;
        if (idx < n) {
            bkt[i] = 255 - min(counts[idx], 255);
            rank[i] = atomicAdd(&lh[bkt[i]], 1);
        }
    }
    __syncthreads();
    if (lh[tid]) lbase[tid] = start + atomicAdd(&dcur[tid], lh[tid]);
    __syncthreads();
#pragma unroll
    for (int i = 0; i < 8; ++i) {
        int idx = base + i;
        if (idx < n) perm[lbase[bkt[i]] + rank[i]] = idx;
    }
}

// Fused gather + GEMM — UNCHANGED (control).
__global__ __launch_bounds__(256) void k_gg(
    const unsigned short* __restrict__ xb, const int2* __restrict__ sedge,
    const int* __restrict__ row_start, const int* __restrict__ perm,
    const unsigned short* __restrict__ Wp, const float* __restrict__ bias,
    float* __restrict__ out, int n) {
    __shared__ __align__(16) unsigned short aggl[32][264];  // 16.5KB
    __shared__ int pnl[32];
    const int tid = threadIdx.x;
    const int lane = tid & 63;
    const int wv = tid >> 6;
    const int base = blockIdx.x * NPB + wv * 8;

    int pn[8], ebeg[8], eend[8];
    int maxd = 0;
#pragma unroll
    for (int j = 0; j < 8; ++j) {
        pn[j] = perm[min(base + j, n - 1)];
        ebeg[j] = row_start[pn[j]];
        eend[j] = row_start[pn[j] + 1];
        maxd = max(maxd, eend[j] - ebeg[j]);
    }
    if (lane == 0) {
#pragma unroll
        for (int j = 0; j < 8; ++j) pnl[wv * 8 + j] = pn[j];
    }
    float4 acc[8];
#pragma unroll
    for (int j = 0; j < 8; ++j) acc[j] = make_float4(0.f, 0.f, 0.f, 0.f);

    for (int it = 0; it < maxd; ++it) {
        int2 ev[8];
        ushort4 xv[8];
#pragma unroll
        for (int j = 0; j < 8; ++j) {
            int e = ebeg[j] + it;
            int ec = max(min(e, eend[j] - 1), 0);  // clamped: always valid
            ev[j] = sedge[ec];
        }
#pragma unroll
        for (int j = 0; j < 8; ++j) {
            xv[j] = *(const ushort4*)&xb[(size_t)ev[j].x * D + lane * 4];
        }
#pragma unroll
        for (int j = 0; j < 8; ++j) {
            float v = (ebeg[j] + it < eend[j]) ? __int_as_float(ev[j].y) : 0.f;
            acc[j].x += v * bf2f(xv[j].x);
            acc[j].y += v * bf2f(xv[j].y);
            acc[j].z += v * bf2f(xv[j].z);
            acc[j].w += v * bf2f(xv[j].w);
        }
    }
#pragma unroll
    for (int j = 0; j < 8; ++j) {
        ushort4 u;
        u.x = f2bf(acc[j].x);
        u.y = f2bf(acc[j].y);
        u.z = f2bf(acc[j].z);
        u.w = f2bf(acc[j].w);
        *(ushort4*)&aggl[wv * 8 + j][lane * 4] = u;
    }
    __syncthreads();

    const int q = lane >> 4, l = lane & 15;
    const int rt = wv >> 1;
    const int cb = (wv & 1) * 8;
    floatx4 gac[8];
#pragma unroll
    for (int i = 0; i < 8; ++i) gac[i] = (floatx4){0.f, 0.f, 0.f, 0.f};
#pragma unroll
    for (int ks = 0; ks < 8; ++ks) {
        short8 a = *(const short8*)&aggl[rt * 16 + l][ks * 32 + q * 8];
#pragma unroll
        for (int i = 0; i < 8; ++i) {
            short8 b = *(const short8*)&Wp[(size_t)(((cb + i) * 8 + ks) * 64 + lane) * 8];
            gac[i] = __builtin_amdgcn_mfma_f32_16x16x32_bf16(a, b, gac[i], 0, 0, 0);
        }
    }
#pragma unroll
    for (int i = 0; i < 8; ++i) {
        int o = (cb + i) * 16 + l;
        float bv = bias[o];
#pragma unroll
        for (int r = 0; r < 4; ++r) {
            int row = rt * 16 + q * 4 + r;
            if (base - wv * 8 + row < n)
                out[(size_t)pnl[row] * D + o] = gac[i][r] + bv;
        }
    }
}

extern "C" void kernel_launch(void* const* d_in, const int* in_sizes, int n_in,
                              void* d_out, int out_size, void* d_ws, size_t ws_size,
                              hipStream_t stream) {
    const float* x    = (const float*)d_in[0];
    const int*   erow = (const int*)d_in[1];
    const int*   ecol = (const int*)d_in[2];
    const float* eval = (const float*)d_in[3];
    const float* W    = (const float*)d_in[4];
    const float* bias = (const float*)d_in[5];
    float* out = (float*)d_out;

    const int n = in_sizes[0] / D;  // 100000
    const int e = in_sizes[1];      // 3200000
    const int nchunk = (e + CHUNK_E - 1) / CHUNK_E;  // 782

    // ws: blkbins[nchunk*NBUCK] | dhist[256] | dcur[256] | btot[NBUCK]
    //     | bstart[NBUCK+1] | counts[n] | row_start[n+1] | perm[n]
    //     | blkoff[nchunk*NBUCK] | staged[e] int2 | sedge[e] int2
    //     | Wp[65536] u16 | xb[n*256] u16
    int* blkbins   = (int*)d_ws;
    int* dhist     = blkbins + (size_t)nchunk * NBUCK;
    int* dcur      = dhist + 256;
    int* btot      = dcur + 256;
    int* bstart    = btot + NBUCK;
    int* counts    = bstart + NBUCK + 1;
    int* row_start = counts + n;
    int* perm      = row_start + n + 1;
    int* blkoff    = perm + n;
    int2* staged   = (int2*)(((uintptr_t)(blkoff + (size_t)nchunk * NBUCK) + 15) & ~(uintptr_t)15);
    int2* sedge    = staged + e;
    unsigned short* Wp = (unsigned short*)(sedge + e);
    unsigned short* xb = Wp + 65536;

    // zero: blkbins + dhist + dcur (contiguous)
    hipMemsetAsync(blkbins, 0, ((size_t)nchunk * NBUCK + 512) * sizeof(int), stream);

    k_prep<<<12500, 256, 0, stream>>>(erow, blkbins, x, xb, W, Wp, e, n);
    k_off<<<NBUCK, 256, 0, stream>>>(blkbins, blkoff, btot, nchunk);
    k_bscan<<<1, 256, 0, stream>>>(btot, bstart, row_start, n);
    k_stage<<<nchunk, 256, 0, stream>>>(erow, ecol, eval, blkoff, bstart, staged, e);
    k_csr<<<NBUCK, 256, 0, stream>>>(staged, bstart, row_start, counts, dhist, sedge, n);
    k_perm<<<49, 256, 0, stream>>>(counts, dhist, dcur, perm, n);
    k_gg<<<(n + NPB - 1) / NPB, 256, 0, stream>>>(xb, sedge, row_start, perm,
                                                  Wp, bias, out, n);
}

// Round 7
// 608.856 us; speedup vs baseline: 1.7747x; 1.0097x over previous
//
#include <hip/hip_runtime.h>
#include <cstdint>
#include <cstddef>

// GraphConvolution: out = (A_sparse @ x) @ W^T + b   (N=100000, E=3.2M, D=256)
// Pipeline (8 launches): memset(2KB) -> prep(chunk bins + castX + castWp)
//   -> off(per-bucket chunk scans) -> bscan(bucket starts) -> stage(LDS
//   bucket reorder) -> csr(row hist/scan + COL-SORT + exact scatter)
//   -> perm(deg-sort) -> gather+GEMM fused (k_gg).
// NOTE: never use the 2nd __launch_bounds__ arg on gather — caps VGPRs ~84,
// forces GBs of scratch spill.
// R4: bf16 x halves per-edge bytes — gather byte-bound. 495->310us.
// R5: degree-sorted node assignment removes max-of-8 padding (310->278).
// R6: block-aggregated counting sort (hot same-address global atomics
//     serialize; never exceed ~100 depth per address).
// R7: fused gather+GEMM via LDS agg tile + fragment-ordered Wp. k_gg=330us.
// R8: bucketed two-level scatter kills write-allocate amplification. 867->699.
// R9: degrees recomputed in k_csr via LDS hist (no global hist atomics). ->615.
// R10(this): (a) per-row edge lists COLUMN-SORTED (extra col-bucket pass in
//   k_csr, L2-resident) — degree-matched waves then sweep x in a narrow
//   column window instead of random, cutting k_gg's 12x L2-miss refetch;
//   (b) k_prep bins whole chunks (782 blocks, plain stores, no global atomics).
#define D 256
#define NPB 32
#define BROWS 512      // rows per bucket
#define NBUCK 196      // ceil(100000/512)
#define CHUNK_E 4096   // edges per staging chunk

typedef __attribute__((ext_vector_type(8))) short short8;
typedef __attribute__((ext_vector_type(4))) float floatx4;

__device__ __forceinline__ unsigned short f2bf(float f) {
    union { float f; unsigned int u; } cv; cv.f = f;
    unsigned int u = cv.u;
    unsigned int r = (u + 0x7fffu + ((u >> 16) & 1u)) >> 16;  // RNE
    return (unsigned short)r;
}

__device__ __forceinline__ float bf2f(unsigned short s) {
    union { unsigned int u; float f; } cv;
    cv.u = ((unsigned int)s) << 16;
    return cv.f;
}

// blocks 0..nchunk-1: bin one whole 4096-edge chunk in LDS (depth ~21/bin),
// then PLAIN stores to blkbins (no global atomics, no memset needed).
// All blocks: castX; first 8192 threads: castWp.
// Wp layout: flat j = ((ct*8 + ks)*64 + q*16 + l), Wp[j*8..+8] =
//   bf16(W[ct*16 + l][ks*32 + q*8 .. +8])  -> B-frag load is 1KB coalesced.
__global__ void k_prep(const int* __restrict__ erow, int* __restrict__ blkbins,
                       const float* __restrict__ x, unsigned short* __restrict__ xb,
                       const float* __restrict__ W, unsigned short* __restrict__ Wp,
                       int e, int n, int nchunk) {
    __shared__ int lb[NBUCK];
    const int tid = threadIdx.x;
    const bool bin_duty = ((int)blockIdx.x < nchunk);  // block-uniform
    if (bin_duty) {
        if (tid < NBUCK) lb[tid] = 0;
        __syncthreads();
        const int ebase = blockIdx.x * CHUNK_E;
#pragma unroll
        for (int i = 0; i < 16; ++i) {
            int idx = ebase + i * 256 + tid;
            if (idx < e) atomicAdd(&lb[erow[idx] >> 9], 1);
        }
    }
    int gid = blockIdx.x * blockDim.x + tid;
    size_t i8 = (size_t)gid * 8;
    if (i8 < (size_t)n * D) {
        float4 a = *(const float4*)&x[i8];
        float4 b = *(const float4*)&x[i8 + 4];
        short8 v;
        v[0] = (short)f2bf(a.x); v[1] = (short)f2bf(a.y);
        v[2] = (short)f2bf(a.z); v[3] = (short)f2bf(a.w);
        v[4] = (short)f2bf(b.x); v[5] = (short)f2bf(b.y);
        v[6] = (short)f2bf(b.z); v[7] = (short)f2bf(b.w);
        *(short8*)&xb[i8] = v;
    }
    if (gid < 8192) {
        int ct = gid >> 9, rem = gid & 511;
        int ks = rem >> 6, ln = rem & 63;
        int q = ln >> 4, l = ln & 15;
        const float* src = &W[(size_t)(ct * 16 + l) * D + ks * 32 + q * 8];
        float4 c = *(const float4*)src;
        float4 d2 = *(const float4*)(src + 4);
        short8 w;
        w[0] = (short)f2bf(c.x); w[1] = (short)f2bf(c.y);
        w[2] = (short)f2bf(c.z); w[3] = (short)f2bf(c.w);
        w[4] = (short)f2bf(d2.x); w[5] = (short)f2bf(d2.y);
        w[6] = (short)f2bf(d2.z); w[7] = (short)f2bf(d2.w);
        *(short8*)&Wp[(size_t)gid * 8] = w;
    }
    if (bin_duty) {
        __syncthreads();
        if (tid < NBUCK) blkbins[blockIdx.x * NBUCK + tid] = lb[tid];
    }
}

// Per-bucket exclusive scan over chunk bins (seeded at 0) -> blkoff; bucket
// total -> btot.
__global__ __launch_bounds__(256) void k_off(
    const int* __restrict__ blkbins, int* __restrict__ blkoff,
    int* __restrict__ btot, int nchunk) {
    __shared__ int sd[256];
    const int tid = threadIdx.x;
    const int bk = blockIdx.x;
    int carry = 0;
    for (int c0 = 0; c0 < nchunk; c0 += 256) {
        int c = c0 + tid;
        int v = (c < nchunk) ? blkbins[c * NBUCK + bk] : 0;
        sd[tid] = v;
        __syncthreads();
        for (int off = 1; off < 256; off <<= 1) {
            int t = (tid >= off) ? sd[tid - off] : 0;
            __syncthreads();
            sd[tid] += t;
            __syncthreads();
        }
        if (c < nchunk) blkoff[c * NBUCK + bk] = carry + sd[tid] - v;
        int tot = sd[255];
        __syncthreads();
        carry += tot;
    }
    if (tid == 0) btot[bk] = carry;
}

// Scan bucket totals -> bstart (exclusive); bstart[NBUCK] = row_start[n] = e.
__global__ void k_bscan(const int* __restrict__ btot, int* __restrict__ bstart,
                        int* __restrict__ row_start, int n) {
    __shared__ int sd[256];
    const int tid = threadIdx.x;
    int v = (tid < NBUCK) ? btot[tid] : 0;
    sd[tid] = v;
    __syncthreads();
    for (int off = 1; off < 256; off <<= 1) {
        int t = (tid >= off) ? sd[tid - off] : 0;
        __syncthreads();
        sd[tid] += t;
        __syncthreads();
    }
    if (tid < NBUCK) bstart[tid] = sd[tid] - v;
    if (tid == 255) {
        bstart[NBUCK] = sd[255];
        row_start[n] = sd[255];
    }
}

// Stage: each 4096-edge chunk reorders its edges bucket-contiguously through
// LDS, then writes coalesced runs to exact precomputed offsets into bufA.
// Payload packs (localrow<<17)|col + val.
__global__ __launch_bounds__(256) void k_stage(
    const int* __restrict__ erow, const int* __restrict__ ecol,
    const float* __restrict__ eval, const int* __restrict__ blkoff,
    const int* __restrict__ bstart, int2* __restrict__ bufA, int e) {
    __shared__ int lb[NBUCK];
    __shared__ int gb[NBUCK];
    __shared__ int sc[256];
    __shared__ unsigned char bid[CHUNK_E];
    __shared__ int2 ebuf[CHUNK_E];  // 32KB
    const int tid = threadIdx.x;
    if (tid < NBUCK) lb[tid] = 0;
    __syncthreads();
    const int ebase = blockIdx.x * CHUNK_E;
    int bk[16], rk[16];
#pragma unroll
    for (int i = 0; i < 16; ++i) {
        int idx = ebase + i * 256 + tid;
        bk[i] = -1;
        if (idx < e) {
            bk[i] = erow[idx] >> 9;
            rk[i] = atomicAdd(&lb[bk[i]], 1);
        }
    }
    __syncthreads();
    int v = (tid < NBUCK) ? lb[tid] : 0;
    sc[tid] = v;
    __syncthreads();
    for (int off = 1; off < 256; off <<= 1) {
        int t = (tid >= off) ? sc[tid - off] : 0;
        __syncthreads();
        sc[tid] += t;
        __syncthreads();
    }
    int loff = sc[tid] - v;  // exclusive
    if (tid < NBUCK) {
        lb[tid] = loff;
        gb[tid] = bstart[tid] + blkoff[blockIdx.x * NBUCK + tid] - loff;
    }
    __syncthreads();
#pragma unroll
    for (int i = 0; i < 16; ++i) {
        if (bk[i] >= 0) {
            int idx = ebase + i * 256 + tid;
            int slot = lb[bk[i]] + rk[i];
            int r = erow[idx];
            ebuf[slot] = make_int2(((r & (BROWS - 1)) << 17) | ecol[idx],
                                   __float_as_int(eval[idx]));
            bid[slot] = (unsigned char)bk[i];
        }
    }
    __syncthreads();
    const int cnt = min(e - ebase, CHUNK_E);
#pragma unroll
    for (int i = 0; i < 16; ++i) {
        int s = i * 256 + tid;
        if (s < cnt) bufA[gb[bid[s]] + s] = ebuf[s];
    }
}

// One block per bucket, all passes inside the bucket's ~130KB L2-resident
// window: (A) LDS row hist + col-bucket hist; scans -> row_start, degrees,
// deg-bin hist, row cursors, col cursors; (A2) bufA -> bufB col-grouped;
// (B) bufB -> bufA exact CSR scatter in col-ascending order (per-row lists
// end up column-sorted -> k_gg sweeps x in a narrow window).
__global__ __launch_bounds__(256) void k_csr(
    int2* __restrict__ bufA, int2* __restrict__ bufB,
    const int* __restrict__ bstart, int* __restrict__ row_start,
    int* __restrict__ counts, int* __restrict__ dhist, int n) {
    __shared__ int h[BROWS];
    __shared__ int ch[256];
    __shared__ int sc[256];
    __shared__ int dh[256];
    const int b = blockIdx.x, tid = threadIdx.x;
    const int r0 = b * BROWS;
    h[tid] = 0; h[tid + 256] = 0; dh[tid] = 0; ch[tid] = 0;
    __syncthreads();
    const int beg = bstart[b];
    const int end = bstart[b + 1];
    for (int idx = beg + tid; idx < end; idx += 256) {
        int sx = bufA[idx].x;
        atomicAdd(&h[((unsigned)sx) >> 17], 1);
        atomicAdd(&ch[(sx & 0x1FFFF) >> 9], 1);
    }
    __syncthreads();
    int a0 = h[tid], a1 = h[tid + 256], c0 = ch[tid];
    // scan rows lower 256
    sc[tid] = a0;
    __syncthreads();
    for (int off = 1; off < 256; off <<= 1) {
        int t = (tid >= off) ? sc[tid - off] : 0;
        __syncthreads();
        sc[tid] += t;
        __syncthreads();
    }
    int incl0 = sc[tid];
    int tot0 = sc[255];
    __syncthreads();
    // scan rows upper 256
    sc[tid] = a1;
    __syncthreads();
    for (int off = 1; off < 256; off <<= 1) {
        int t = (tid >= off) ? sc[tid - off] : 0;
        __syncthreads();
        sc[tid] += t;
        __syncthreads();
    }
    int incl1 = sc[tid];
    __syncthreads();
    // scan col bins
    sc[tid] = c0;
    __syncthreads();
    for (int off = 1; off < 256; off <<= 1) {
        int t = (tid >= off) ? sc[tid - off] : 0;
        __syncthreads();
        sc[tid] += t;
        __syncthreads();
    }
    int inclc = sc[tid];
    __syncthreads();
    int cur0 = beg + incl0 - a0;
    int cur1 = beg + tot0 + incl1 - a1;
    h[tid] = cur0;
    h[tid + 256] = cur1;
    ch[tid] = beg + inclc - c0;  // col-bin cursor
    if (r0 + tid < n) {
        row_start[r0 + tid] = cur0;
        counts[r0 + tid] = a0;
        atomicAdd(&dh[255 - min(a0, 255)], 1);
    }
    if (r0 + 256 + tid < n) {
        row_start[r0 + 256 + tid] = cur1;
        counts[r0 + 256 + tid] = a1;
        atomicAdd(&dh[255 - min(a1, 255)], 1);
    }
    __syncthreads();
    if (dh[tid]) atomicAdd(&dhist[tid], dh[tid]);
    // A2: col-grouped permute bufA -> bufB
    for (int idx = beg + tid; idx < end; idx += 256) {
        int2 sv = bufA[idx];
        int p = atomicAdd(&ch[(sv.x & 0x1FFFF) >> 9], 1);
        bufB[p] = sv;
    }
    __syncthreads();
    // B: exact CSR scatter in col-ascending order; unpack to (col,val)
    for (int idx = beg + tid; idx < end; idx += 256) {
        int2 sv = bufB[idx];
        int p = atomicAdd(&h[((unsigned)sv.x) >> 17], 1);
        bufA[p] = make_int2(sv.x & 0x1FFFF, sv.y);
    }
}

// Build descending-degree perm. Each block redundantly scans dhist in LDS for
// bin starts, then block-aggregated reservation (1 global atomic per
// (block,bin) — never hot).
__global__ __launch_bounds__(256) void k_perm(
    const int* __restrict__ counts, const int* __restrict__ dhist,
    int* __restrict__ dcur, int* __restrict__ perm, int n) {
    __shared__ int st[256];
    __shared__ int lh[256];
    __shared__ int lbase[256];
    const int tid = threadIdx.x;
    lh[tid] = 0;
    int dv = dhist[tid];
    st[tid] = dv;
    __syncthreads();
    for (int off = 1; off < 256; off <<= 1) {
        int t = (tid >= off) ? st[tid - off] : 0;
        __syncthreads();
        st[tid] += t;
        __syncthreads();
    }
    int start = st[tid] - dv;  // exclusive bin start
    const int base = blockIdx.x * 2048 + tid * 8;
    int bkt[8], rank[8];
#pragma unroll
    for (int i = 0; i < 8; ++i) {
        int idx = base + i;
        if (idx < n) {
            bkt[i] = 255 - min(counts[idx], 255);
            rank[i] = atomicAdd(&lh[bkt[i]], 1);
        }
    }
    __syncthreads();
    if (lh[tid]) lbase[tid] = start + atomicAdd(&dcur[tid], lh[tid]);
    __syncthreads();
#pragma unroll
    for (int i = 0; i < 8; ++i) {
        int idx = base + i;
        if (idx < n) perm[lbase[bkt[i]] + rank[i]] = idx;
    }
}

// Fused gather + GEMM — code UNCHANGED; input edge lists now column-sorted.
__global__ __launch_bounds__(256) void k_gg(
    const unsigned short* __restrict__ xb, const int2* __restrict__ sedge,
    const int* __restrict__ row_start, const int* __restrict__ perm,
    const unsigned short* __restrict__ Wp, const float* __restrict__ bias,
    float* __restrict__ out, int n) {
    __shared__ __align__(16) unsigned short aggl[32][264];  // 16.5KB
    __shared__ int pnl[32];
    const int tid = threadIdx.x;
    const int lane = tid & 63;
    const int wv = tid >> 6;
    const int base = blockIdx.x * NPB + wv * 8;

    int pn[8], ebeg[8], eend[8];
    int maxd = 0;
#pragma unroll
    for (int j = 0; j < 8; ++j) {
        pn[j] = perm[min(base + j, n - 1)];
        ebeg[j] = row_start[pn[j]];
        eend[j] = row_start[pn[j] + 1];
        maxd = max(maxd, eend[j] - ebeg[j]);
    }
    if (lane == 0) {
#pragma unroll
        for (int j = 0; j < 8; ++j) pnl[wv * 8 + j] = pn[j];
    }
    float4 acc[8];
#pragma unroll
    for (int j = 0; j < 8; ++j) acc[j] = make_float4(0.f, 0.f, 0.f, 0.f);

    for (int it = 0; it < maxd; ++it) {
        int2 ev[8];
        ushort4 xv[8];
#pragma unroll
        for (int j = 0; j < 8; ++j) {
            int e = ebeg[j] + it;
            int ec = max(min(e, eend[j] - 1), 0);  // clamped: always valid
            ev[j] = sedge[ec];
        }
#pragma unroll
        for (int j = 0; j < 8; ++j) {
            xv[j] = *(const ushort4*)&xb[(size_t)ev[j].x * D + lane * 4];
        }
#pragma unroll
        for (int j = 0; j < 8; ++j) {
            float v = (ebeg[j] + it < eend[j]) ? __int_as_float(ev[j].y) : 0.f;
            acc[j].x += v * bf2f(xv[j].x);
            acc[j].y += v * bf2f(xv[j].y);
            acc[j].z += v * bf2f(xv[j].z);
            acc[j].w += v * bf2f(xv[j].w);
        }
    }
#pragma unroll
    for (int j = 0; j < 8; ++j) {
        ushort4 u;
        u.x = f2bf(acc[j].x);
        u.y = f2bf(acc[j].y);
        u.z = f2bf(acc[j].z);
        u.w = f2bf(acc[j].w);
        *(ushort4*)&aggl[wv * 8 + j][lane * 4] = u;
    }
    __syncthreads();

    const int q = lane >> 4, l = lane & 15;
    const int rt = wv >> 1;
    const int cb = (wv & 1) * 8;
    floatx4 gac[8];
#pragma unroll
    for (int i = 0; i < 8; ++i) gac[i] = (floatx4){0.f, 0.f, 0.f, 0.f};
#pragma unroll
    for (int ks = 0; ks < 8; ++ks) {
        short8 a = *(const short8*)&aggl[rt * 16 + l][ks * 32 + q * 8];
#pragma unroll
        for (int i = 0; i < 8; ++i) {
            short8 b = *(const short8*)&Wp[(size_t)(((cb + i) * 8 + ks) * 64 + lane) * 8];
            gac[i] = __builtin_amdgcn_mfma_f32_16x16x32_bf16(a, b, gac[i], 0, 0, 0);
        }
    }
#pragma unroll
    for (int i = 0; i < 8; ++i) {
        int o = (cb + i) * 16 + l;
        float bv = bias[o];
#pragma unroll
        for (int r = 0; r < 4; ++r) {
            int row = rt * 16 + q * 4 + r;
            if (base - wv * 8 + row < n)
                out[(size_t)pnl[row] * D + o] = gac[i][r] + bv;
        }
    }
}

extern "C" void kernel_launch(void* const* d_in, const int* in_sizes, int n_in,
                              void* d_out, int out_size, void* d_ws, size_t ws_size,
                              hipStream_t stream) {
    const float* x    = (const float*)d_in[0];
    const int*   erow = (const int*)d_in[1];
    const int*   ecol = (const int*)d_in[2];
    const float* eval = (const float*)d_in[3];
    const float* W    = (const float*)d_in[4];
    const float* bias = (const float*)d_in[5];
    float* out = (float*)d_out;

    const int n = in_sizes[0] / D;  // 100000
    const int e = in_sizes[1];      // 3200000
    const int nchunk = (e + CHUNK_E - 1) / CHUNK_E;  // 782

    // ws: dhist[256] | dcur[256] | btot[NBUCK] | bstart[NBUCK+1] | counts[n]
    //     | row_start[n+1] | perm[n] | blkbins[nchunk*NBUCK]
    //     | blkoff[nchunk*NBUCK] | bufA[e] int2 | bufB[e] int2
    //     | Wp[65536] u16 | xb[n*256] u16
    int* dhist     = (int*)d_ws;
    int* dcur      = dhist + 256;
    int* btot      = dcur + 256;
    int* bstart    = btot + NBUCK;
    int* counts    = bstart + NBUCK + 1;
    int* row_start = counts + n;
    int* perm      = row_start + n + 1;
    int* blkbins   = perm + n;
    int* blkoff    = blkbins + (size_t)nchunk * NBUCK;
    int2* bufA     = (int2*)(((uintptr_t)(blkoff + (size_t)nchunk * NBUCK) + 15) & ~(uintptr_t)15);
    int2* bufB     = bufA + e;
    unsigned short* Wp = (unsigned short*)(bufB + e);
    unsigned short* xb = Wp + 65536;

    // zero: dhist + dcur only (blkbins fully written by plain stores now)
    hipMemsetAsync(dhist, 0, 512 * sizeof(int), stream);

    k_prep<<<12500, 256, 0, stream>>>(erow, blkbins, x, xb, W, Wp, e, n, nchunk);
    k_off<<<NBUCK, 256, 0, stream>>>(blkbins, blkoff, btot, nchunk);
    k_bscan<<<1, 256, 0, stream>>>(btot, bstart, row_start, n);
    k_stage<<<nchunk, 256, 0, stream>>>(erow, ecol, eval, blkoff, bstart, bufA, e);
    k_csr<<<NBUCK, 256, 0, stream>>>(bufA, bufB, bstart, row_start, counts, dhist, n);
    k_perm<<<49, 256, 0, stream>>>(counts, dhist, dcur, perm, n);
    k_gg<<<(n + NPB - 1) / NPB, 256, 0, stream>>>(xb, bufA, row_start, perm,
                                                  Wp, bias, out, n);
}